// Round 1
// baseline (1369.794 us; speedup 1.0000x reference)
//
#include <hip/hip_runtime.h>

#define NPTS 8192
#define DIM 128
#define NCLS 128
#define KSEL 17      // k+1 smallest define the threshold
#define ROWS 32      // rows per block (two 16-row MFMA sets)
#define CAPW 36      // per-(wave,row) LDS candidate capacity
#define SEG  32      // per-(row,segment) scratch segment
#define NSEG 8       // column segments (1024 cols each)
#define NT   16      // tiles per wave (256 cols / 16)
#define MBLK 1024    // merge blocks (8 rows each)
#define BIG 3.0e38f

typedef short bf16x8 __attribute__((ext_vector_type(8)));
typedef float f32x4 __attribute__((ext_vector_type(4)));

__device__ __forceinline__ unsigned short f2bf(float f) {
  unsigned int u = __float_as_uint(f);
  u += 0x7fffu + ((u >> 16) & 1u);   // round-to-nearest-even
  return (unsigned short)(u >> 16);
}

// order-preserving float <-> uint map (total order, exact inverse)
__device__ __forceinline__ unsigned flipF(float f) {
  unsigned u = __float_as_uint(f);
  return (u & 0x80000000u) ? ~u : (u | 0x80000000u);
}
__device__ __forceinline__ float unflipF(unsigned k) {
  unsigned u = (k & 0x80000000u) ? (k & 0x7fffffffu) : ~k;
  return __uint_as_float(u);
}

// exact KSEL-th smallest of the 128 values {a,b} x 64 lanes (ballot radix descent)
// values may be negative (val-space) -> full 32-bit descent
__device__ __forceinline__ float kth17_2(float a, float b) {
  const unsigned ka = flipF(a), kb = flipF(b);
  unsigned ans = 0;
  for (int bit = 31; bit >= 0; --bit) {
    unsigned mid = ans | (1u << bit);
    int c = __popcll(__ballot(ka < mid)) + __popcll(__ballot(kb < mid));
    if (c < KSEL) ans = mid;
  }
  return unflipF(ans);   // largest v with count(<v) < KSEL == KSEL-th smallest
}

// exact KSEL-th smallest of the 256 values {a,b,c,d} x 64 lanes.
// all inputs are >= 0 here (encoded d2 with flag stripped, or BIG) ->
// flipped keys all have bit31 set; start descent at bit 30.
__device__ __forceinline__ float kth17_4(float a, float b, float c, float d) {
  const unsigned ka = flipF(a), kb = flipF(b), kc = flipF(c), kd = flipF(d);
  unsigned ans = 0x80000000u;
  for (int bit = 30; bit >= 0; --bit) {
    unsigned mid = ans | (1u << bit);
    int cc = __popcll(__ballot(ka < mid)) + __popcll(__ballot(kb < mid)) +
             __popcll(__ballot(kc < mid)) + __popcll(__ballot(kd < mid));
    if (cc < KSEL) ans = mid;
  }
  return unflipF(ans);
}

// ---- prep: blocks 0..2047 build bf16 X + exact norms; block 2048: class stats (LDS,
// vectorized 4-wide target loads).
__global__ void prep(const float* __restrict__ X, const long long* __restrict__ targets,
                     unsigned short* __restrict__ Xb, float* __restrict__ sqv,
                     int* __restrict__ tgt, int* __restrict__ ccount,
                     int* __restrict__ j0a, int* __restrict__ j1a) {
  const int tid = threadIdx.x;
  if (blockIdx.x == 2048) {
    __shared__ int cc[NCLS], c0[NCLS], c1[NCLS];
    if (tid < NCLS) { cc[tid] = 0; c0[tid] = 0x7fffffff; c1[tid] = 0x7fffffff; }
    __syncthreads();
    for (int base = tid * 4; base < NPTS; base += 1024) {
      const long long* p = targets + base;
#pragma unroll
      for (int k = 0; k < 4; k++) {
        int c = (int)p[k];
        tgt[base + k] = c;
        atomicAdd(&cc[c], 1);
        atomicMin(&c0[c], base + k);
      }
    }
    __syncthreads();
    for (int base = tid * 4; base < NPTS; base += 1024) {
#pragma unroll
      for (int k = 0; k < 4; k++) {
        int c = tgt[base + k];
        if (base + k != c0[c]) atomicMin(&c1[c], base + k);
      }
    }
    __syncthreads();
    if (tid < NCLS) { ccount[tid] = cc[tid]; j0a[tid] = c0[tid]; j1a[tid] = c1[tid]; }
    return;
  }
  const int w = tid >> 6, lane = tid & 63;
  const int gw = blockIdx.x * 4 + w;
  const float* xr = X + (size_t)gw * DIM;
  float a = xr[lane], b = xr[lane + 64];
  Xb[(size_t)gw * DIM + lane] = f2bf(a);
  Xb[(size_t)gw * DIM + lane + 64] = f2bf(b);
  float s = a * a + b * b;
#pragma unroll
  for (int off = 32; off; off >>= 1) s += __shfl_xor(s, off);
  if (lane == 0) sqv[gw] = s;
}

// ---- two-sweep kNN: grid 2048 = 256 row-groups(32 rows) x 8 column-segments(1024).
// 8 blocks/CU (LDS 19KB, VGPR<=64 via launch_bounds(256,8)) -> 8 waves/SIMD for
// latency hiding (was grid-capped at 4). Wave w scans cols [seg*1024 + w*256, +256);
// per iteration TWO 16-col tiles are loaded together then consumed by 16 MFMAs.
// val = sqj - 2*G (sqi-invariant ordering per row).
__global__ __launch_bounds__(256, 8) void knn_main(
    const unsigned short* __restrict__ Xb, const float* __restrict__ sqv,
    const int* __restrict__ tgt, float* __restrict__ scr, int* __restrict__ cscr) {
  __shared__ float sh[4608];   // union: cand[32][128] (16KB) / bufD[4][32][CAPW] (18KB)
  __shared__ int   cnt[4][ROWS];
  __shared__ float Uv[ROWS];

  const int tid = threadIdx.x;
  const int w = tid >> 6;
  const int lane = tid & 63;
  const int quad = lane >> 4;
  const int l16 = lane & 15;
  const int rg = blockIdx.x >> 3;
  const int seg8 = blockIdx.x & 7;
  const int rbase = rg * ROWS;
  const int colbase = seg8 * 1024 + w * 256;

  // A fragments: 2 sets x K=128. 16x16x32 bf16: A[m=lane&15][k=quad*8+j]
  bf16x8 afrag[2][4];
#pragma unroll
  for (int s = 0; s < 2; s++) {
    const unsigned short* arow = Xb + (size_t)(rbase + s * 16 + l16) * DIM + quad * 8;
#pragma unroll
    for (int kb = 0; kb < 4; kb++) afrag[s][kb] = *(const bf16x8*)(arow + kb * 32);
  }
  float sqi[2][4]; int ti[2][4];
#pragma unroll
  for (int s = 0; s < 2; s++)
#pragma unroll
    for (int r = 0; r < 4; r++) {
      int rr = rbase + s * 16 + quad * 4 + r;
      sqi[s][r] = sqv[rr]; ti[s][r] = tgt[rr];
    }

  // wave-uniform diagonal tile per set (or -1)
  int tdiag[2];
#pragma unroll
  for (int s = 0; s < 2; s++) {
    int d = rbase + s * 16 - colbase;
    tdiag[s] = (d >= 0 && d < 256) ? (d >> 4) : -1;
  }

  const unsigned short* bbase = Xb + (size_t)(colbase + l16) * DIM + quad * 8;
  const float* sqp = sqv + colbase + l16;
  const int*   tgp = tgt + colbase + l16;

  // ---- sweep 1: per-lane two smallest vals per row; 2 tiles per iteration
  float m1[2][4], m2[2][4];
#pragma unroll
  for (int s = 0; s < 2; s++)
#pragma unroll
    for (int r = 0; r < 4; r++) { m1[s][r] = BIG; m2[s][r] = BIG; }
  for (int t = 0; t < NT; t += 2) {
    const unsigned short* p0 = bbase + (size_t)t * (16 * DIM);
    bf16x8 b0[4], b1[4];
#pragma unroll
    for (int kb = 0; kb < 4; kb++) {
      b0[kb] = *(const bf16x8*)(p0 + kb * 32);
      b1[kb] = *(const bf16x8*)(p0 + 16 * DIM + kb * 32);
    }
    const float sq0 = sqp[t * 16], sq1 = sqp[(t + 1) * 16];
    f32x4 a00 = {0.f,0.f,0.f,0.f}, a10 = {0.f,0.f,0.f,0.f};
    f32x4 a01 = {0.f,0.f,0.f,0.f}, a11 = {0.f,0.f,0.f,0.f};
#pragma unroll
    for (int kb = 0; kb < 4; kb++) {
      a00 = __builtin_amdgcn_mfma_f32_16x16x32_bf16(afrag[0][kb], b0[kb], a00, 0, 0, 0);
      a10 = __builtin_amdgcn_mfma_f32_16x16x32_bf16(afrag[1][kb], b0[kb], a10, 0, 0, 0);
      a01 = __builtin_amdgcn_mfma_f32_16x16x32_bf16(afrag[0][kb], b1[kb], a01, 0, 0, 0);
      a11 = __builtin_amdgcn_mfma_f32_16x16x32_bf16(afrag[1][kb], b1[kb], a11, 0, 0, 0);
    }
#pragma unroll
    for (int s = 0; s < 2; s++) {
#pragma unroll
      for (int r = 0; r < 4; r++) {
        float v0 = fmaf(-2.0f, (s ? a10[r] : a00[r]), sq0);
        float v1 = fmaf(-2.0f, (s ? a11[r] : a01[r]), sq1);
        if (t == tdiag[s] && l16 == quad * 4 + r) v0 = BIG;
        if (t + 1 == tdiag[s] && l16 == quad * 4 + r) v1 = BIG;
        m2[s][r] = fminf(m2[s][r], fmaxf(m1[s][r], v0));
        m1[s][r] = fminf(m1[s][r], v0);
        m2[s][r] = fminf(m2[s][r], fmaxf(m1[s][r], v1));
        m1[s][r] = fminf(m1[s][r], v1);
      }
    }
  }
  // publish min2: per row 4 waves x 16 lanes x 2 = 128 candidates (val-space)
#pragma unroll
  for (int s = 0; s < 2; s++)
#pragma unroll
    for (int r = 0; r < 4; r++) {
      int row = s * 16 + quad * 4 + r;
      sh[row * 128 + w * 32 + l16 * 2] = m1[s][r];
      sh[row * 128 + w * 32 + l16 * 2 + 1] = m2[s][r];
    }
  __syncthreads();

  // U[row] = 17th smallest of the 128-candidate subset (radix-select; >= segment t17)
  for (int ri = 0; ri < 8; ri++) {
    int row = w * 8 + ri;
    float v17 = kth17_2(sh[row * 128 + lane], sh[row * 128 + 64 + lane]);
    if (lane == 0) Uv[row] = v17;
  }
  __syncthreads();
  float Ur[2][4];
#pragma unroll
  for (int s = 0; s < 2; s++)
#pragma unroll
    for (int r = 0; r < 4; r++) Ur[s][r] = Uv[s * 16 + quad * 4 + r];
  if (lane < ROWS) cnt[w][lane] = 0;   // wave-local; ordered before this wave's appends

  // ---- sweep 2: append val <= U (encode d2 = val + sqi, flag in sign bit)
  for (int t = 0; t < NT; t += 2) {
    const unsigned short* p0 = bbase + (size_t)t * (16 * DIM);
    bf16x8 b0[4], b1[4];
#pragma unroll
    for (int kb = 0; kb < 4; kb++) {
      b0[kb] = *(const bf16x8*)(p0 + kb * 32);
      b1[kb] = *(const bf16x8*)(p0 + 16 * DIM + kb * 32);
    }
    const float sq0 = sqp[t * 16], sq1 = sqp[(t + 1) * 16];
    const int tj0 = tgp[t * 16], tj1 = tgp[(t + 1) * 16];
    f32x4 a00 = {0.f,0.f,0.f,0.f}, a10 = {0.f,0.f,0.f,0.f};
    f32x4 a01 = {0.f,0.f,0.f,0.f}, a11 = {0.f,0.f,0.f,0.f};
#pragma unroll
    for (int kb = 0; kb < 4; kb++) {
      a00 = __builtin_amdgcn_mfma_f32_16x16x32_bf16(afrag[0][kb], b0[kb], a00, 0, 0, 0);
      a10 = __builtin_amdgcn_mfma_f32_16x16x32_bf16(afrag[1][kb], b0[kb], a10, 0, 0, 0);
      a01 = __builtin_amdgcn_mfma_f32_16x16x32_bf16(afrag[0][kb], b1[kb], a01, 0, 0, 0);
      a11 = __builtin_amdgcn_mfma_f32_16x16x32_bf16(afrag[1][kb], b1[kb], a11, 0, 0, 0);
    }
    float v0[2][4], v1[2][4]; bool any = false;
#pragma unroll
    for (int s = 0; s < 2; s++) {
#pragma unroll
      for (int r = 0; r < 4; r++) {
        float x0 = fmaf(-2.0f, (s ? a10[r] : a00[r]), sq0);
        float x1 = fmaf(-2.0f, (s ? a11[r] : a01[r]), sq1);
        if (t == tdiag[s] && l16 == quad * 4 + r) x0 = BIG;
        if (t + 1 == tdiag[s] && l16 == quad * 4 + r) x1 = BIG;
        v0[s][r] = x0; v1[s][r] = x1;
        any |= (x0 <= Ur[s][r]) | (x1 <= Ur[s][r]);
      }
    }
    if (__any(any)) {
#pragma unroll
      for (int s = 0; s < 2; s++) {
#pragma unroll
        for (int r = 0; r < 4; r++) {
          const int rl = s * 16 + quad * 4 + r;
          if (v0[s][r] <= Ur[s][r]) {
            int pos = atomicAdd(&cnt[w][rl], 1);
            if (pos < CAPW) {
              unsigned enc = __float_as_uint(fmaxf(v0[s][r] + sqi[s][r], 0.0f));
              if (tj0 == ti[s][r]) enc |= 0x80000000u;
              sh[(w * ROWS + rl) * CAPW + pos] = __uint_as_float(enc);
            }
          }
          if (v1[s][r] <= Ur[s][r]) {
            int pos = atomicAdd(&cnt[w][rl], 1);
            if (pos < CAPW) {
              unsigned enc = __float_as_uint(fmaxf(v1[s][r] + sqi[s][r], 0.0f));
              if (tj1 == ti[s][r]) enc |= 0x80000000u;
              sh[(w * ROWS + rl) * CAPW + pos] = __uint_as_float(enc);
            }
          }
        }
      }
    }
  }
  __syncthreads();

  // ---- finalize: raw-copy candidate lists (common) or 17-extract (overflow, rare)
  for (int rl = 0; rl < ROWS; rl++) {
    const int c0 = min(cnt[0][rl], CAPW), c1 = min(cnt[1][rl], CAPW),
              c2 = min(cnt[2][rl], CAPW), c3 = min(cnt[3][rl], CAPW);
    const int tot = c0 + c1 + c2 + c3;
    const int grow = rbase + rl;
    float* srow = scr + (size_t)grow * (NSEG * SEG) + seg8 * SEG;
    if (tot <= SEG) {
      const int pre = (w > 0 ? c0 : 0) + (w > 1 ? c1 : 0) + (w > 2 ? c2 : 0);
      const int myc = (w == 0) ? c0 : ((w == 1) ? c1 : ((w == 2) ? c2 : c3));
      if (lane < myc) srow[pre + lane] = sh[(w * ROWS + rl) * CAPW + lane];
      if (tid == 0) cscr[grow * NSEG + seg8] = tot;
    } else if (w == (rl & 3)) {
      float e[4]; int m[4];
#pragma unroll
      for (int ww = 0; ww < 4; ww++) {
        int n = min(cnt[ww][rl], CAPW);
        if (lane < n) {
          unsigned u = __float_as_uint(sh[(ww * ROWS + rl) * CAPW + lane]);
          m[ww] = (int)(u >> 31); e[ww] = __uint_as_float(u & 0x7fffffffu);
        } else { e[ww] = BIG; m[ww] = 0; }
      }
      for (int round = 0; round < KSEL; round++) {
        float v = e[0]; int idx = lane;
        if (e[1] < v) { v = e[1]; idx = lane | (1 << 6); }
        if (e[2] < v) { v = e[2]; idx = lane | (2 << 6); }
        if (e[3] < v) { v = e[3]; idx = lane | (3 << 6); }
#pragma unroll
        for (int off = 32; off; off >>= 1) {
          float ov = __shfl_xor(v, off);
          int   oi = __shfl_xor(idx, off);
          if (ov < v || (ov == v && oi < idx)) { v = ov; idx = oi; }
        }
        if ((idx & 63) == lane) {
          int s = idx >> 6;
          unsigned ub = __float_as_uint(e[s]);
          if (m[s]) ub |= 0x80000000u;
          srow[round] = __uint_as_float(ub);
          e[s] = BIG;
        }
      }
      if (lane == 0) cscr[grow * NSEG + seg8] = KSEL;
    }
  }
}

// ---- per-row merge of 8 segment-lists (<=256 candidates, 4 per lane) + loss epilogue.
// NO fences, NO global atomics: per-block partials to pacc (plain stores).
__global__ __launch_bounds__(256) void knn_merge(
    const float* __restrict__ scr, const int* __restrict__ cscr,
    const float* __restrict__ sqv, const int* __restrict__ tgt,
    const int* __restrict__ ccount, const int* __restrict__ j0a,
    const int* __restrict__ j1a, const float* __restrict__ X32,
    float* __restrict__ pacc) {
  __shared__ float blockAcc[4];
  const int tid = threadIdx.x;
  const int w = tid >> 6;
  const int lane = tid & 63;
  if (tid < 4) blockAcc[tid] = 0.0f;
  __syncthreads();
  for (int ri = 0; ri < 2; ri++) {
    const int grow = blockIdx.x * 8 + w * 2 + ri;
    const float* srow = scr + (size_t)grow * (NSEG * SEG);
    const int h = lane >> 5, li = lane & 31;
    float e[4]; int mm[4];
#pragma unroll
    for (int j = 0; j < 4; j++) {
      const int seg = j * 2 + h;
      const int cj = cscr[grow * NSEG + seg];
      if (li < cj) {
        unsigned u = __float_as_uint(srow[seg * SEG + li]);
        mm[j] = (int)(u >> 31); e[j] = __uint_as_float(u & 0x7fffffffu);
      } else { e[j] = BIG; mm[j] = 0; }
    }
    // exact 17th smallest of the union (radix-select over 4 values/lane)
    const float t17 = kth17_4(e[0], e[1], e[2], e[3]);
    float pls = 0.0f, nls = 0.0f; int cp = 0, cn = 0;
#pragma unroll
    for (int j = 0; j < 4; j++) {
      const bool s = (e[j] < t17);                        // strict, matches reference
      const float x = s ? expf(-sqrtf(fmaxf(e[j], 1e-12f))) : 0.0f;
      if (mm[j]) { pls += x; cp += (int)s; }
      else       { nls += x; cn += (int)s; }
    }
    int cpn = cp * 65536 + cn;
#pragma unroll
    for (int off = 32; off; off >>= 1) {
      pls += __shfl_xor(pls, off); nls += __shfl_xor(nls, off);
      cpn += __shfl_xor(cpn, off);
    }
    const int cpt = cpn >> 16, cnt_ = cpn & 0xffff;
    const int c = tgt[grow];
    const int ncl = ccount[c];
    const bool valid = (ncl > 1) && (ncl < NPTS);
    if (valid) {
      float pos_eff;
      if (cpt == 0) {
        const int jf = (grow == j0a[c]) ? j1a[c] : j0a[c];
        const float* xi = X32 + (size_t)grow * DIM;
        const float* xj = X32 + (size_t)jf * DIM;
        float pp = xi[lane] * xj[lane] + xi[lane + 64] * xj[lane + 64];
#pragma unroll
        for (int off = 32; off; off >>= 1) pp += __shfl_xor(pp, off);
        const float fb2 = sqv[grow] + sqv[jf] - 2.0f * pp;
        pos_eff = expf(-sqrtf(fmaxf(fb2, 1e-12f)));
      } else {
        pos_eff = pls;
      }
      if (lane == 0) {
        const float loss_i = -logf(pos_eff / (pos_eff + nls));
        const int cpa = (cpt == 0) ? 1 : cpt;
        atomicAdd(&blockAcc[0], loss_i);
        atomicAdd(&blockAcc[1], (cpa > cnt_) ? 1.0f : 0.0f);
        atomicAdd(&blockAcc[2], (float)cpt);
        atomicAdd(&blockAcc[3], (float)cnt_);
      }
    }
  }
  __syncthreads();
  if (tid < 4) pacc[blockIdx.x * 4 + tid] = blockAcc[tid];
}

// ---- final reduction: 1 block sums 1024 x 4 partials, writes out
__global__ void fin(const float* __restrict__ pacc, float* __restrict__ out) {
  __shared__ float red[256];
  const int tid = threadIdx.x;
  const int c = tid & 3, b0 = tid >> 2;
  float s = 0.0f;
  for (int b = b0; b < MBLK; b += 64) s += pacc[b * 4 + c];
  red[tid] = s;
  __syncthreads();
  if (tid < 4) {
    float t = 0.0f;
    for (int i = tid; i < 256; i += 4) t += red[i];
    out[tid] = t * (1.0f / (float)NPTS);
  }
}

extern "C" void kernel_launch(void* const* d_in, const int* in_sizes, int n_in,
                              void* d_out, int out_size, void* d_ws, size_t ws_size,
                              hipStream_t stream) {
  const float* X = (const float*)d_in[0];
  const long long* targets = (const long long*)d_in[1];
  float* out = (float*)d_out;

  char* ws = (char*)d_ws;
  unsigned short* Xb = (unsigned short*)ws;                        // 2 MiB
  float* sqv    = (float*)   (ws + (2u << 20));                    // 32 KiB
  int*   tgt    = (int*)     (ws + (2u << 20) + (32u << 10));      // 32 KiB
  int*   ccount = (int*)     (ws + (2u << 20) + (64u << 10));      // 512 B
  int*   j0a    = (int*)     (ws + (2u << 20) + (65u << 10));      // 512 B
  int*   j1a    = (int*)     (ws + (2u << 20) + (66u << 10));      // 512 B
  float* pacc   = (float*)   (ws + (2u << 20) + (68u << 10));      // 16 KiB (1024 x 4)
  float* scr = (float*)(ws + (2u << 20) + (128u << 10));           // 8192*8*SEG*4 = 8 MiB
  int* cscr  = (int*)  (ws + (2u << 20) + (128u << 10) +
                        (size_t)NPTS * NSEG * SEG * 4);            // 256 KiB

  prep<<<2049, 256, 0, stream>>>(X, targets, Xb, sqv, tgt, ccount, j0a, j1a);
  knn_main<<<2048, 256, 0, stream>>>(Xb, sqv, tgt, scr, cscr);
  knn_merge<<<MBLK, 256, 0, stream>>>(scr, cscr, sqv, tgt, ccount, j0a, j1a, X, pacc);
  fin<<<1, 256, 0, stream>>>(pacc, out);
}

// Round 2
// 258.126 us; speedup vs baseline: 5.3067x; 5.3067x over previous
//
#include <hip/hip_runtime.h>

#define NPTS 8192
#define DIM 128
#define NCLS 128
#define KSEL 17      // k+1 smallest define the threshold
#define ROWS 32      // rows per block (two 16-row MFMA sets)
#define CAPW 36      // per-(wave,row) LDS candidate capacity
#define SEG  32      // per-(row,segment) scratch segment
#define NSEG 8       // column segments (1024 cols each)
#define NT   16      // tiles per wave (256 cols / 16)
#define MBLK 1024    // merge blocks (8 rows each)
#define BIG 3.0e38f

typedef short bf16x8 __attribute__((ext_vector_type(8)));
typedef float f32x4 __attribute__((ext_vector_type(4)));

__device__ __forceinline__ unsigned short f2bf(float f) {
  unsigned int u = __float_as_uint(f);
  u += 0x7fffu + ((u >> 16) & 1u);   // round-to-nearest-even
  return (unsigned short)(u >> 16);
}

// order-preserving float <-> uint map (total order, exact inverse)
__device__ __forceinline__ unsigned flipF(float f) {
  unsigned u = __float_as_uint(f);
  return (u & 0x80000000u) ? ~u : (u | 0x80000000u);
}
__device__ __forceinline__ float unflipF(unsigned k) {
  unsigned u = (k & 0x80000000u) ? (k & 0x7fffffffu) : ~k;
  return __uint_as_float(u);
}

// exact KSEL-th smallest of the 128 values {a,b} x 64 lanes (ballot radix descent)
// values may be negative (val-space) -> full 32-bit descent
__device__ __forceinline__ float kth17_2(float a, float b) {
  const unsigned ka = flipF(a), kb = flipF(b);
  unsigned ans = 0;
  for (int bit = 31; bit >= 0; --bit) {
    unsigned mid = ans | (1u << bit);
    int c = __popcll(__ballot(ka < mid)) + __popcll(__ballot(kb < mid));
    if (c < KSEL) ans = mid;
  }
  return unflipF(ans);   // largest v with count(<v) < KSEL == KSEL-th smallest
}

// exact KSEL-th smallest of the 256 values {a,b,c,d} x 64 lanes.
// all inputs are >= 0 here (encoded d2 with flag stripped, or BIG) ->
// flipped keys all have bit31 set; start descent at bit 30.
__device__ __forceinline__ float kth17_4(float a, float b, float c, float d) {
  const unsigned ka = flipF(a), kb = flipF(b), kc = flipF(c), kd = flipF(d);
  unsigned ans = 0x80000000u;
  for (int bit = 30; bit >= 0; --bit) {
    unsigned mid = ans | (1u << bit);
    int cc = __popcll(__ballot(ka < mid)) + __popcll(__ballot(kb < mid)) +
             __popcll(__ballot(kc < mid)) + __popcll(__ballot(kd < mid));
    if (cc < KSEL) ans = mid;
  }
  return unflipF(ans);
}

// ---- prep: blocks 0..2047 build bf16 X + exact norms; block 2048: class stats (LDS,
// vectorized 4-wide target loads).
__global__ void prep(const float* __restrict__ X, const long long* __restrict__ targets,
                     unsigned short* __restrict__ Xb, float* __restrict__ sqv,
                     int* __restrict__ tgt, int* __restrict__ ccount,
                     int* __restrict__ j0a, int* __restrict__ j1a) {
  const int tid = threadIdx.x;
  if (blockIdx.x == 2048) {
    __shared__ int cc[NCLS], c0[NCLS], c1[NCLS];
    if (tid < NCLS) { cc[tid] = 0; c0[tid] = 0x7fffffff; c1[tid] = 0x7fffffff; }
    __syncthreads();
    for (int base = tid * 4; base < NPTS; base += 1024) {
      const long long* p = targets + base;
#pragma unroll
      for (int k = 0; k < 4; k++) {
        int c = (int)p[k];
        tgt[base + k] = c;
        atomicAdd(&cc[c], 1);
        atomicMin(&c0[c], base + k);
      }
    }
    __syncthreads();
    for (int base = tid * 4; base < NPTS; base += 1024) {
#pragma unroll
      for (int k = 0; k < 4; k++) {
        int c = tgt[base + k];
        if (base + k != c0[c]) atomicMin(&c1[c], base + k);
      }
    }
    __syncthreads();
    if (tid < NCLS) { ccount[tid] = cc[tid]; j0a[tid] = c0[tid]; j1a[tid] = c1[tid]; }
    return;
  }
  const int w = tid >> 6, lane = tid & 63;
  const int gw = blockIdx.x * 4 + w;
  const float* xr = X + (size_t)gw * DIM;
  float a = xr[lane], b = xr[lane + 64];
  Xb[(size_t)gw * DIM + lane] = f2bf(a);
  Xb[(size_t)gw * DIM + lane + 64] = f2bf(b);
  float s = a * a + b * b;
#pragma unroll
  for (int off = 32; off; off >>= 1) s += __shfl_xor(s, off);
  if (lane == 0) sqv[gw] = s;
}

// ---- two-sweep kNN: grid 2048 = 256 row-groups(32 rows) x 8 column-segments(1024).
// launch_bounds(256,3): same bound that yields the 64-VGPR no-spill codegen (round-0);
// (256,8) forced a 32-VGPR clamp -> 3.9 GB scratch spill traffic, 8.6x regression.
// LDS 19.4KB allows 8 blocks/CU; grid 2048 offers 8 blocks/CU of work so the HW can
// raise waves/SIMD beyond the old grid-capped 4 if the 64-reg allocation permits.
// Wave w scans cols [seg*1024 + w*256, +256); per iteration TWO 16-col tiles are
// loaded together then consumed by 16 MFMAs. val = sqj - 2*G (sqi-invariant per row).
__global__ __launch_bounds__(256, 3) void knn_main(
    const unsigned short* __restrict__ Xb, const float* __restrict__ sqv,
    const int* __restrict__ tgt, float* __restrict__ scr, int* __restrict__ cscr) {
  __shared__ float sh[4608];   // union: cand[32][128] (16KB) / bufD[4][32][CAPW] (18KB)
  __shared__ int   cnt[4][ROWS];
  __shared__ float Uv[ROWS];

  const int tid = threadIdx.x;
  const int w = tid >> 6;
  const int lane = tid & 63;
  const int quad = lane >> 4;
  const int l16 = lane & 15;
  const int rg = blockIdx.x >> 3;
  const int seg8 = blockIdx.x & 7;
  const int rbase = rg * ROWS;
  const int colbase = seg8 * 1024 + w * 256;

  // A fragments: 2 sets x K=128. 16x16x32 bf16: A[m=lane&15][k=quad*8+j]
  bf16x8 afrag[2][4];
#pragma unroll
  for (int s = 0; s < 2; s++) {
    const unsigned short* arow = Xb + (size_t)(rbase + s * 16 + l16) * DIM + quad * 8;
#pragma unroll
    for (int kb = 0; kb < 4; kb++) afrag[s][kb] = *(const bf16x8*)(arow + kb * 32);
  }
  float sqi[2][4]; int ti[2][4];
#pragma unroll
  for (int s = 0; s < 2; s++)
#pragma unroll
    for (int r = 0; r < 4; r++) {
      int rr = rbase + s * 16 + quad * 4 + r;
      sqi[s][r] = sqv[rr]; ti[s][r] = tgt[rr];
    }

  // wave-uniform diagonal tile per set (or -1)
  int tdiag[2];
#pragma unroll
  for (int s = 0; s < 2; s++) {
    int d = rbase + s * 16 - colbase;
    tdiag[s] = (d >= 0 && d < 256) ? (d >> 4) : -1;
  }

  const unsigned short* bbase = Xb + (size_t)(colbase + l16) * DIM + quad * 8;
  const float* sqp = sqv + colbase + l16;
  const int*   tgp = tgt + colbase + l16;

  // ---- sweep 1: per-lane two smallest vals per row; 2 tiles per iteration
  float m1[2][4], m2[2][4];
#pragma unroll
  for (int s = 0; s < 2; s++)
#pragma unroll
    for (int r = 0; r < 4; r++) { m1[s][r] = BIG; m2[s][r] = BIG; }
  for (int t = 0; t < NT; t += 2) {
    const unsigned short* p0 = bbase + (size_t)t * (16 * DIM);
    bf16x8 b0[4], b1[4];
#pragma unroll
    for (int kb = 0; kb < 4; kb++) {
      b0[kb] = *(const bf16x8*)(p0 + kb * 32);
      b1[kb] = *(const bf16x8*)(p0 + 16 * DIM + kb * 32);
    }
    const float sq0 = sqp[t * 16], sq1 = sqp[(t + 1) * 16];
    f32x4 a00 = {0.f,0.f,0.f,0.f}, a10 = {0.f,0.f,0.f,0.f};
    f32x4 a01 = {0.f,0.f,0.f,0.f}, a11 = {0.f,0.f,0.f,0.f};
#pragma unroll
    for (int kb = 0; kb < 4; kb++) {
      a00 = __builtin_amdgcn_mfma_f32_16x16x32_bf16(afrag[0][kb], b0[kb], a00, 0, 0, 0);
      a10 = __builtin_amdgcn_mfma_f32_16x16x32_bf16(afrag[1][kb], b0[kb], a10, 0, 0, 0);
      a01 = __builtin_amdgcn_mfma_f32_16x16x32_bf16(afrag[0][kb], b1[kb], a01, 0, 0, 0);
      a11 = __builtin_amdgcn_mfma_f32_16x16x32_bf16(afrag[1][kb], b1[kb], a11, 0, 0, 0);
    }
#pragma unroll
    for (int s = 0; s < 2; s++) {
#pragma unroll
      for (int r = 0; r < 4; r++) {
        float v0 = fmaf(-2.0f, (s ? a10[r] : a00[r]), sq0);
        float v1 = fmaf(-2.0f, (s ? a11[r] : a01[r]), sq1);
        if (t == tdiag[s] && l16 == quad * 4 + r) v0 = BIG;
        if (t + 1 == tdiag[s] && l16 == quad * 4 + r) v1 = BIG;
        m2[s][r] = fminf(m2[s][r], fmaxf(m1[s][r], v0));
        m1[s][r] = fminf(m1[s][r], v0);
        m2[s][r] = fminf(m2[s][r], fmaxf(m1[s][r], v1));
        m1[s][r] = fminf(m1[s][r], v1);
      }
    }
  }
  // publish min2: per row 4 waves x 16 lanes x 2 = 128 candidates (val-space)
#pragma unroll
  for (int s = 0; s < 2; s++)
#pragma unroll
    for (int r = 0; r < 4; r++) {
      int row = s * 16 + quad * 4 + r;
      sh[row * 128 + w * 32 + l16 * 2] = m1[s][r];
      sh[row * 128 + w * 32 + l16 * 2 + 1] = m2[s][r];
    }
  __syncthreads();

  // U[row] = 17th smallest of the 128-candidate subset (radix-select; >= segment t17)
  for (int ri = 0; ri < 8; ri++) {
    int row = w * 8 + ri;
    float v17 = kth17_2(sh[row * 128 + lane], sh[row * 128 + 64 + lane]);
    if (lane == 0) Uv[row] = v17;
  }
  __syncthreads();
  float Ur[2][4];
#pragma unroll
  for (int s = 0; s < 2; s++)
#pragma unroll
    for (int r = 0; r < 4; r++) Ur[s][r] = Uv[s * 16 + quad * 4 + r];
  if (lane < ROWS) cnt[w][lane] = 0;   // wave-local; ordered before this wave's appends

  // ---- sweep 2: append val <= U (encode d2 = val + sqi, flag in sign bit)
  for (int t = 0; t < NT; t += 2) {
    const unsigned short* p0 = bbase + (size_t)t * (16 * DIM);
    bf16x8 b0[4], b1[4];
#pragma unroll
    for (int kb = 0; kb < 4; kb++) {
      b0[kb] = *(const bf16x8*)(p0 + kb * 32);
      b1[kb] = *(const bf16x8*)(p0 + 16 * DIM + kb * 32);
    }
    const float sq0 = sqp[t * 16], sq1 = sqp[(t + 1) * 16];
    const int tj0 = tgp[t * 16], tj1 = tgp[(t + 1) * 16];
    f32x4 a00 = {0.f,0.f,0.f,0.f}, a10 = {0.f,0.f,0.f,0.f};
    f32x4 a01 = {0.f,0.f,0.f,0.f}, a11 = {0.f,0.f,0.f,0.f};
#pragma unroll
    for (int kb = 0; kb < 4; kb++) {
      a00 = __builtin_amdgcn_mfma_f32_16x16x32_bf16(afrag[0][kb], b0[kb], a00, 0, 0, 0);
      a10 = __builtin_amdgcn_mfma_f32_16x16x32_bf16(afrag[1][kb], b0[kb], a10, 0, 0, 0);
      a01 = __builtin_amdgcn_mfma_f32_16x16x32_bf16(afrag[0][kb], b1[kb], a01, 0, 0, 0);
      a11 = __builtin_amdgcn_mfma_f32_16x16x32_bf16(afrag[1][kb], b1[kb], a11, 0, 0, 0);
    }
    float v0[2][4], v1[2][4]; bool any = false;
#pragma unroll
    for (int s = 0; s < 2; s++) {
#pragma unroll
      for (int r = 0; r < 4; r++) {
        float x0 = fmaf(-2.0f, (s ? a10[r] : a00[r]), sq0);
        float x1 = fmaf(-2.0f, (s ? a11[r] : a01[r]), sq1);
        if (t == tdiag[s] && l16 == quad * 4 + r) x0 = BIG;
        if (t + 1 == tdiag[s] && l16 == quad * 4 + r) x1 = BIG;
        v0[s][r] = x0; v1[s][r] = x1;
        any |= (x0 <= Ur[s][r]) | (x1 <= Ur[s][r]);
      }
    }
    if (__any(any)) {
#pragma unroll
      for (int s = 0; s < 2; s++) {
#pragma unroll
        for (int r = 0; r < 4; r++) {
          const int rl = s * 16 + quad * 4 + r;
          if (v0[s][r] <= Ur[s][r]) {
            int pos = atomicAdd(&cnt[w][rl], 1);
            if (pos < CAPW) {
              unsigned enc = __float_as_uint(fmaxf(v0[s][r] + sqi[s][r], 0.0f));
              if (tj0 == ti[s][r]) enc |= 0x80000000u;
              sh[(w * ROWS + rl) * CAPW + pos] = __uint_as_float(enc);
            }
          }
          if (v1[s][r] <= Ur[s][r]) {
            int pos = atomicAdd(&cnt[w][rl], 1);
            if (pos < CAPW) {
              unsigned enc = __float_as_uint(fmaxf(v1[s][r] + sqi[s][r], 0.0f));
              if (tj1 == ti[s][r]) enc |= 0x80000000u;
              sh[(w * ROWS + rl) * CAPW + pos] = __uint_as_float(enc);
            }
          }
        }
      }
    }
  }
  __syncthreads();

  // ---- finalize: raw-copy candidate lists (common) or 17-extract (overflow, rare)
  for (int rl = 0; rl < ROWS; rl++) {
    const int c0 = min(cnt[0][rl], CAPW), c1 = min(cnt[1][rl], CAPW),
              c2 = min(cnt[2][rl], CAPW), c3 = min(cnt[3][rl], CAPW);
    const int tot = c0 + c1 + c2 + c3;
    const int grow = rbase + rl;
    float* srow = scr + (size_t)grow * (NSEG * SEG) + seg8 * SEG;
    if (tot <= SEG) {
      const int pre = (w > 0 ? c0 : 0) + (w > 1 ? c1 : 0) + (w > 2 ? c2 : 0);
      const int myc = (w == 0) ? c0 : ((w == 1) ? c1 : ((w == 2) ? c2 : c3));
      if (lane < myc) srow[pre + lane] = sh[(w * ROWS + rl) * CAPW + lane];
      if (tid == 0) cscr[grow * NSEG + seg8] = tot;
    } else if (w == (rl & 3)) {
      float e[4]; int m[4];
#pragma unroll
      for (int ww = 0; ww < 4; ww++) {
        int n = min(cnt[ww][rl], CAPW);
        if (lane < n) {
          unsigned u = __float_as_uint(sh[(ww * ROWS + rl) * CAPW + lane]);
          m[ww] = (int)(u >> 31); e[ww] = __uint_as_float(u & 0x7fffffffu);
        } else { e[ww] = BIG; m[ww] = 0; }
      }
      for (int round = 0; round < KSEL; round++) {
        float v = e[0]; int idx = lane;
        if (e[1] < v) { v = e[1]; idx = lane | (1 << 6); }
        if (e[2] < v) { v = e[2]; idx = lane | (2 << 6); }
        if (e[3] < v) { v = e[3]; idx = lane | (3 << 6); }
#pragma unroll
        for (int off = 32; off; off >>= 1) {
          float ov = __shfl_xor(v, off);
          int   oi = __shfl_xor(idx, off);
          if (ov < v || (ov == v && oi < idx)) { v = ov; idx = oi; }
        }
        if ((idx & 63) == lane) {
          int s = idx >> 6;
          unsigned ub = __float_as_uint(e[s]);
          if (m[s]) ub |= 0x80000000u;
          srow[round] = __uint_as_float(ub);
          e[s] = BIG;
        }
      }
      if (lane == 0) cscr[grow * NSEG + seg8] = KSEL;
    }
  }
}

// ---- per-row merge of 8 segment-lists (<=256 candidates, 4 per lane) + loss epilogue.
// NO fences, NO global atomics: per-block partials to pacc (plain stores).
__global__ __launch_bounds__(256) void knn_merge(
    const float* __restrict__ scr, const int* __restrict__ cscr,
    const float* __restrict__ sqv, const int* __restrict__ tgt,
    const int* __restrict__ ccount, const int* __restrict__ j0a,
    const int* __restrict__ j1a, const float* __restrict__ X32,
    float* __restrict__ pacc) {
  __shared__ float blockAcc[4];
  const int tid = threadIdx.x;
  const int w = tid >> 6;
  const int lane = tid & 63;
  if (tid < 4) blockAcc[tid] = 0.0f;
  __syncthreads();
  for (int ri = 0; ri < 2; ri++) {
    const int grow = blockIdx.x * 8 + w * 2 + ri;
    const float* srow = scr + (size_t)grow * (NSEG * SEG);
    const int h = lane >> 5, li = lane & 31;
    float e[4]; int mm[4];
#pragma unroll
    for (int j = 0; j < 4; j++) {
      const int seg = j * 2 + h;
      const int cj = cscr[grow * NSEG + seg];
      if (li < cj) {
        unsigned u = __float_as_uint(srow[seg * SEG + li]);
        mm[j] = (int)(u >> 31); e[j] = __uint_as_float(u & 0x7fffffffu);
      } else { e[j] = BIG; mm[j] = 0; }
    }
    // exact 17th smallest of the union (radix-select over 4 values/lane)
    const float t17 = kth17_4(e[0], e[1], e[2], e[3]);
    float pls = 0.0f, nls = 0.0f; int cp = 0, cn = 0;
#pragma unroll
    for (int j = 0; j < 4; j++) {
      const bool s = (e[j] < t17);                        // strict, matches reference
      const float x = s ? expf(-sqrtf(fmaxf(e[j], 1e-12f))) : 0.0f;
      if (mm[j]) { pls += x; cp += (int)s; }
      else       { nls += x; cn += (int)s; }
    }
    int cpn = cp * 65536 + cn;
#pragma unroll
    for (int off = 32; off; off >>= 1) {
      pls += __shfl_xor(pls, off); nls += __shfl_xor(nls, off);
      cpn += __shfl_xor(cpn, off);
    }
    const int cpt = cpn >> 16, cnt_ = cpn & 0xffff;
    const int c = tgt[grow];
    const int ncl = ccount[c];
    const bool valid = (ncl > 1) && (ncl < NPTS);
    if (valid) {
      float pos_eff;
      if (cpt == 0) {
        const int jf = (grow == j0a[c]) ? j1a[c] : j0a[c];
        const float* xi = X32 + (size_t)grow * DIM;
        const float* xj = X32 + (size_t)jf * DIM;
        float pp = xi[lane] * xj[lane] + xi[lane + 64] * xj[lane + 64];
#pragma unroll
        for (int off = 32; off; off >>= 1) pp += __shfl_xor(pp, off);
        const float fb2 = sqv[grow] + sqv[jf] - 2.0f * pp;
        pos_eff = expf(-sqrtf(fmaxf(fb2, 1e-12f)));
      } else {
        pos_eff = pls;
      }
      if (lane == 0) {
        const float loss_i = -logf(pos_eff / (pos_eff + nls));
        const int cpa = (cpt == 0) ? 1 : cpt;
        atomicAdd(&blockAcc[0], loss_i);
        atomicAdd(&blockAcc[1], (cpa > cnt_) ? 1.0f : 0.0f);
        atomicAdd(&blockAcc[2], (float)cpt);
        atomicAdd(&blockAcc[3], (float)cnt_);
      }
    }
  }
  __syncthreads();
  if (tid < 4) pacc[blockIdx.x * 4 + tid] = blockAcc[tid];
}

// ---- final reduction: 1 block sums 1024 x 4 partials, writes out
__global__ void fin(const float* __restrict__ pacc, float* __restrict__ out) {
  __shared__ float red[256];
  const int tid = threadIdx.x;
  const int c = tid & 3, b0 = tid >> 2;
  float s = 0.0f;
  for (int b = b0; b < MBLK; b += 64) s += pacc[b * 4 + c];
  red[tid] = s;
  __syncthreads();
  if (tid < 4) {
    float t = 0.0f;
    for (int i = tid; i < 256; i += 4) t += red[i];
    out[tid] = t * (1.0f / (float)NPTS);
  }
}

extern "C" void kernel_launch(void* const* d_in, const int* in_sizes, int n_in,
                              void* d_out, int out_size, void* d_ws, size_t ws_size,
                              hipStream_t stream) {
  const float* X = (const float*)d_in[0];
  const long long* targets = (const long long*)d_in[1];
  float* out = (float*)d_out;

  char* ws = (char*)d_ws;
  unsigned short* Xb = (unsigned short*)ws;                        // 2 MiB
  float* sqv    = (float*)   (ws + (2u << 20));                    // 32 KiB
  int*   tgt    = (int*)     (ws + (2u << 20) + (32u << 10));      // 32 KiB
  int*   ccount = (int*)     (ws + (2u << 20) + (64u << 10));      // 512 B
  int*   j0a    = (int*)     (ws + (2u << 20) + (65u << 10));      // 512 B
  int*   j1a    = (int*)     (ws + (2u << 20) + (66u << 10));      // 512 B
  float* pacc   = (float*)   (ws + (2u << 20) + (68u << 10));      // 16 KiB (1024 x 4)
  float* scr = (float*)(ws + (2u << 20) + (128u << 10));           // 8192*8*SEG*4 = 8 MiB
  int* cscr  = (int*)  (ws + (2u << 20) + (128u << 10) +
                        (size_t)NPTS * NSEG * SEG * 4);            // 256 KiB

  prep<<<2049, 256, 0, stream>>>(X, targets, Xb, sqv, tgt, ccount, j0a, j1a);
  knn_main<<<2048, 256, 0, stream>>>(Xb, sqv, tgt, scr, cscr);
  knn_merge<<<MBLK, 256, 0, stream>>>(scr, cscr, sqv, tgt, ccount, j0a, j1a, X, pacc);
  fin<<<1, 256, 0, stream>>>(pacc, out);
}

// Round 3
// 233.205 us; speedup vs baseline: 5.8738x; 1.1069x over previous
//
#include <hip/hip_runtime.h>

#define NPTS 8192
#define DIM 128
#define NCLS 128
#define KSEL 17      // k+1 smallest define the threshold
#define ROWS 32      // rows per block (two 16-row MFMA sets)
#define CAPW 40      // per-(wave,row) LDS candidate capacity
#define SEG  32      // per-(row,quarter) scratch segment
#define NT   32      // tiles per wave (512 cols / 16)
#define MBLK 512     // merge blocks
#define BIG 3.0e38f

typedef short bf16x8 __attribute__((ext_vector_type(8)));
typedef float f32x4 __attribute__((ext_vector_type(4)));

__device__ __forceinline__ unsigned short f2bf(float f) {
  unsigned int u = __float_as_uint(f);
  u += 0x7fffu + ((u >> 16) & 1u);   // round-to-nearest-even
  return (unsigned short)(u >> 16);
}

// order-preserving float <-> uint map (total order, exact inverse)
__device__ __forceinline__ unsigned flipF(float f) {
  unsigned u = __float_as_uint(f);
  return (u & 0x80000000u) ? ~u : (u | 0x80000000u);
}
__device__ __forceinline__ float unflipF(unsigned k) {
  unsigned u = (k & 0x80000000u) ? (k & 0x7fffffffu) : ~k;
  return __uint_as_float(u);
}

// exact KSEL-th smallest of 64 values (1/lane), ballot radix descent.
// values may be negative (val-space) -> full 32-bit descent.
__device__ __forceinline__ float kth17_1(float a) {
  const unsigned ka = flipF(a);
  unsigned ans = 0;
  for (int bit = 31; bit >= 0; --bit) {
    unsigned mid = ans | (1u << bit);
    if (__popcll(__ballot(ka < mid)) < KSEL) ans = mid;
  }
  return unflipF(ans);   // largest v with count(<v) < KSEL == KSEL-th smallest
}

// exact KSEL-th smallest of the 128 values {a,b} x 64 lanes
__device__ __forceinline__ float kth17_2(float a, float b) {
  const unsigned ka = flipF(a), kb = flipF(b);
  unsigned ans = 0;
  for (int bit = 31; bit >= 0; --bit) {
    unsigned mid = ans | (1u << bit);
    int c = __popcll(__ballot(ka < mid)) + __popcll(__ballot(kb < mid));
    if (c < KSEL) ans = mid;
  }
  return unflipF(ans);
}

// ---- prep: blocks 0..2047 build bf16 X + exact norms; block 2048: class stats (LDS,
// vectorized 4-wide target loads).
__global__ void prep(const float* __restrict__ X, const long long* __restrict__ targets,
                     unsigned short* __restrict__ Xb, float* __restrict__ sqv,
                     int* __restrict__ tgt, int* __restrict__ ccount,
                     int* __restrict__ j0a, int* __restrict__ j1a) {
  const int tid = threadIdx.x;
  if (blockIdx.x == 2048) {
    __shared__ int cc[NCLS], c0[NCLS], c1[NCLS];
    if (tid < NCLS) { cc[tid] = 0; c0[tid] = 0x7fffffff; c1[tid] = 0x7fffffff; }
    __syncthreads();
    for (int base = tid * 4; base < NPTS; base += 1024) {
      const long long* p = targets + base;
#pragma unroll
      for (int k = 0; k < 4; k++) {
        int c = (int)p[k];
        tgt[base + k] = c;
        atomicAdd(&cc[c], 1);
        atomicMin(&c0[c], base + k);
      }
    }
    __syncthreads();
    for (int base = tid * 4; base < NPTS; base += 1024) {
#pragma unroll
      for (int k = 0; k < 4; k++) {
        int c = tgt[base + k];
        if (base + k != c0[c]) atomicMin(&c1[c], base + k);
      }
    }
    __syncthreads();
    if (tid < NCLS) { ccount[tid] = cc[tid]; j0a[tid] = c0[tid]; j1a[tid] = c1[tid]; }
    return;
  }
  const int w = tid >> 6, lane = tid & 63;
  const int gw = blockIdx.x * 4 + w;
  const float* xr = X + (size_t)gw * DIM;
  float a = xr[lane], b = xr[lane + 64];
  Xb[(size_t)gw * DIM + lane] = f2bf(a);
  Xb[(size_t)gw * DIM + lane + 64] = f2bf(b);
  float s = a * a + b * b;
#pragma unroll
  for (int off = 32; off; off >>= 1) s += __shfl_xor(s, off);
  if (lane == 0) sqv[gw] = s;
}

// ---- two-sweep kNN: grid 1024 = 256 row-groups(32 rows) x 4 column-quarters.
// Proven round-0 geometry (4 blocks/CU; <=128 VGPR costs no occupancy here).
// New in this version:
//  (a) software-rotated B prefetch: next tile-pair's 8 loads issue right after the
//      MFMAs consume the current pair, BEFORE the epilogue -> vmcnt wait lands at the
//      next iteration's first use; epilogue + sibling waves sit in the latency shadow.
//  (b) sweep-1 keeps min-1/lane (not min-2): U = 17th of 64 lane-minima, still an
//      upper bound on the true quarter-t17 (subset property; self stays masked).
//      Looser U only grows sweep-2 appends ~17->20/row-quarter; overflow -> exact path.
//  (c) diagonal masking behind a wave-uniform branch (1 of 16 iterations).
// val = sqj - 2*G (sqi-invariant ordering per row).
__global__ __launch_bounds__(256, 3) void knn_main(
    const unsigned short* __restrict__ Xb, const float* __restrict__ sqv,
    const int* __restrict__ tgt, float* __restrict__ scr, int* __restrict__ cscr) {
  __shared__ float sh[5120];   // union: pub[32][64] (8KB) / bufD[4][32][CAPW] (20KB)
  __shared__ int   cnt[4][ROWS];
  __shared__ float Uv[ROWS];

  const int tid = threadIdx.x;
  const int w = tid >> 6;
  const int lane = tid & 63;
  const int quad = lane >> 4;
  const int l16 = lane & 15;
  const int rg = blockIdx.x >> 2;
  const int quarter = blockIdx.x & 3;
  const int rbase = rg * ROWS;
  const int colbase = quarter * 2048 + w * 512;

  // A fragments: 2 sets x K=128. 16x16x32 bf16: A[m=lane&15][k=quad*8+j]
  bf16x8 afrag[2][4];
#pragma unroll
  for (int s = 0; s < 2; s++) {
    const unsigned short* arow = Xb + (size_t)(rbase + s * 16 + l16) * DIM + quad * 8;
#pragma unroll
    for (int kb = 0; kb < 4; kb++) afrag[s][kb] = *(const bf16x8*)(arow + kb * 32);
  }
  float sqi[2][4]; int ti[2][4];
#pragma unroll
  for (int s = 0; s < 2; s++)
#pragma unroll
    for (int r = 0; r < 4; r++) {
      int rr = rbase + s * 16 + quad * 4 + r;
      sqi[s][r] = sqv[rr]; ti[s][r] = tgt[rr];
    }

  // wave-uniform diagonal tile per set (or -1)
  int tdiag[2];
#pragma unroll
  for (int s = 0; s < 2; s++) {
    int d = rbase + s * 16 - colbase;
    tdiag[s] = (d >= 0 && d < 512) ? (d >> 4) : -1;
  }

  const unsigned short* bbase = Xb + (size_t)(colbase + l16) * DIM + quad * 8;
  const float* sqp = sqv + colbase + l16;
  const int*   tgp = tgt + colbase + l16;

  // ---- sweep 1: per-lane min-1 per row; 2 tiles per iteration, prefetched
  float m1[2][4];
#pragma unroll
  for (int s = 0; s < 2; s++)
#pragma unroll
    for (int r = 0; r < 4; r++) m1[s][r] = BIG;

  bf16x8 cb0[4], cb1[4];
#pragma unroll
  for (int kb = 0; kb < 4; kb++) {
    cb0[kb] = *(const bf16x8*)(bbase + kb * 32);
    cb1[kb] = *(const bf16x8*)(bbase + 16 * DIM + kb * 32);
  }
  float sq0 = sqp[0], sq1 = sqp[16];
  for (int t = 0; t < NT; t += 2) {
    f32x4 a00 = {0.f,0.f,0.f,0.f}, a10 = {0.f,0.f,0.f,0.f};
    f32x4 a01 = {0.f,0.f,0.f,0.f}, a11 = {0.f,0.f,0.f,0.f};
#pragma unroll
    for (int kb = 0; kb < 4; kb++) {
      a00 = __builtin_amdgcn_mfma_f32_16x16x32_bf16(afrag[0][kb], cb0[kb], a00, 0, 0, 0);
      a10 = __builtin_amdgcn_mfma_f32_16x16x32_bf16(afrag[1][kb], cb0[kb], a10, 0, 0, 0);
      a01 = __builtin_amdgcn_mfma_f32_16x16x32_bf16(afrag[0][kb], cb1[kb], a01, 0, 0, 0);
      a11 = __builtin_amdgcn_mfma_f32_16x16x32_bf16(afrag[1][kb], cb1[kb], a11, 0, 0, 0);
    }
    // prefetch next pair (clamped reload of t=0 on the last iteration)
    const int tn = (t + 2 < NT) ? t + 2 : 0;
    const unsigned short* pn = bbase + (size_t)tn * (16 * DIM);
    bf16x8 nb0[4], nb1[4];
#pragma unroll
    for (int kb = 0; kb < 4; kb++) {
      nb0[kb] = *(const bf16x8*)(pn + kb * 32);
      nb1[kb] = *(const bf16x8*)(pn + 16 * DIM + kb * 32);
    }
    const float nsq0 = sqp[tn * 16], nsq1 = sqp[tn * 16 + 16];
    // epilogue (diagonal handled in the rare uniform branch)
    if (((unsigned)(tdiag[0] - t) < 2u) || ((unsigned)(tdiag[1] - t) < 2u)) {
#pragma unroll
      for (int s = 0; s < 2; s++) {
#pragma unroll
        for (int r = 0; r < 4; r++) {
          float v0 = fmaf(-2.0f, (s ? a10[r] : a00[r]), sq0);
          float v1 = fmaf(-2.0f, (s ? a11[r] : a01[r]), sq1);
          if (t == tdiag[s] && l16 == quad * 4 + r) v0 = BIG;
          if (t + 1 == tdiag[s] && l16 == quad * 4 + r) v1 = BIG;
          m1[s][r] = fminf(m1[s][r], fminf(v0, v1));
        }
      }
    } else {
#pragma unroll
      for (int s = 0; s < 2; s++) {
#pragma unroll
        for (int r = 0; r < 4; r++) {
          float v0 = fmaf(-2.0f, (s ? a10[r] : a00[r]), sq0);
          float v1 = fmaf(-2.0f, (s ? a11[r] : a01[r]), sq1);
          m1[s][r] = fminf(m1[s][r], fminf(v0, v1));
        }
      }
    }
    sq0 = nsq0; sq1 = nsq1;
#pragma unroll
    for (int kb = 0; kb < 4; kb++) { cb0[kb] = nb0[kb]; cb1[kb] = nb1[kb]; }
  }
  // publish min-1: per row 4 waves x 16 lanes = 64 candidates (val-space)
#pragma unroll
  for (int s = 0; s < 2; s++)
#pragma unroll
    for (int r = 0; r < 4; r++)
      sh[(s * 16 + quad * 4 + r) * 64 + w * 16 + l16] = m1[s][r];
  __syncthreads();

  // U[row] = 17th smallest of the 64-candidate subset (radix-select; >= quarter t17)
  for (int ri = 0; ri < 8; ri++) {
    int row = w * 8 + ri;
    float v17 = kth17_1(sh[row * 64 + lane]);
    if (lane == 0) Uv[row] = v17;
  }
  __syncthreads();
  float Ur[2][4];
#pragma unroll
  for (int s = 0; s < 2; s++)
#pragma unroll
    for (int r = 0; r < 4; r++) Ur[s][r] = Uv[s * 16 + quad * 4 + r];
  if (lane < ROWS) cnt[w][lane] = 0;   // wave-local; ordered before this wave's appends

  // ---- sweep 2: append val <= U (encode d2 = val + sqi, flag in sign bit); prefetched
#pragma unroll
  for (int kb = 0; kb < 4; kb++) {
    cb0[kb] = *(const bf16x8*)(bbase + kb * 32);
    cb1[kb] = *(const bf16x8*)(bbase + 16 * DIM + kb * 32);
  }
  sq0 = sqp[0]; sq1 = sqp[16];
  int tj0 = tgp[0], tj1 = tgp[16];
  for (int t = 0; t < NT; t += 2) {
    f32x4 a00 = {0.f,0.f,0.f,0.f}, a10 = {0.f,0.f,0.f,0.f};
    f32x4 a01 = {0.f,0.f,0.f,0.f}, a11 = {0.f,0.f,0.f,0.f};
#pragma unroll
    for (int kb = 0; kb < 4; kb++) {
      a00 = __builtin_amdgcn_mfma_f32_16x16x32_bf16(afrag[0][kb], cb0[kb], a00, 0, 0, 0);
      a10 = __builtin_amdgcn_mfma_f32_16x16x32_bf16(afrag[1][kb], cb0[kb], a10, 0, 0, 0);
      a01 = __builtin_amdgcn_mfma_f32_16x16x32_bf16(afrag[0][kb], cb1[kb], a01, 0, 0, 0);
      a11 = __builtin_amdgcn_mfma_f32_16x16x32_bf16(afrag[1][kb], cb1[kb], a11, 0, 0, 0);
    }
    const int tn = (t + 2 < NT) ? t + 2 : 0;
    const unsigned short* pn = bbase + (size_t)tn * (16 * DIM);
    bf16x8 nb0[4], nb1[4];
#pragma unroll
    for (int kb = 0; kb < 4; kb++) {
      nb0[kb] = *(const bf16x8*)(pn + kb * 32);
      nb1[kb] = *(const bf16x8*)(pn + 16 * DIM + kb * 32);
    }
    const float nsq0 = sqp[tn * 16], nsq1 = sqp[tn * 16 + 16];
    const int ntj0 = tgp[tn * 16], ntj1 = tgp[tn * 16 + 16];

    float v0[2][4], v1[2][4]; bool any = false;
    if (((unsigned)(tdiag[0] - t) < 2u) || ((unsigned)(tdiag[1] - t) < 2u)) {
#pragma unroll
      for (int s = 0; s < 2; s++) {
#pragma unroll
        for (int r = 0; r < 4; r++) {
          float x0 = fmaf(-2.0f, (s ? a10[r] : a00[r]), sq0);
          float x1 = fmaf(-2.0f, (s ? a11[r] : a01[r]), sq1);
          if (t == tdiag[s] && l16 == quad * 4 + r) x0 = BIG;
          if (t + 1 == tdiag[s] && l16 == quad * 4 + r) x1 = BIG;
          v0[s][r] = x0; v1[s][r] = x1;
          any |= (x0 <= Ur[s][r]) | (x1 <= Ur[s][r]);
        }
      }
    } else {
#pragma unroll
      for (int s = 0; s < 2; s++) {
#pragma unroll
        for (int r = 0; r < 4; r++) {
          float x0 = fmaf(-2.0f, (s ? a10[r] : a00[r]), sq0);
          float x1 = fmaf(-2.0f, (s ? a11[r] : a01[r]), sq1);
          v0[s][r] = x0; v1[s][r] = x1;
          any |= (x0 <= Ur[s][r]) | (x1 <= Ur[s][r]);
        }
      }
    }
    if (__any(any)) {
#pragma unroll
      for (int s = 0; s < 2; s++) {
#pragma unroll
        for (int r = 0; r < 4; r++) {
          const int rl = s * 16 + quad * 4 + r;
          if (v0[s][r] <= Ur[s][r]) {
            int pos = atomicAdd(&cnt[w][rl], 1);
            if (pos < CAPW) {
              unsigned enc = __float_as_uint(fmaxf(v0[s][r] + sqi[s][r], 0.0f));
              if (tj0 == ti[s][r]) enc |= 0x80000000u;
              sh[(w * ROWS + rl) * CAPW + pos] = __uint_as_float(enc);
            }
          }
          if (v1[s][r] <= Ur[s][r]) {
            int pos = atomicAdd(&cnt[w][rl], 1);
            if (pos < CAPW) {
              unsigned enc = __float_as_uint(fmaxf(v1[s][r] + sqi[s][r], 0.0f));
              if (tj1 == ti[s][r]) enc |= 0x80000000u;
              sh[(w * ROWS + rl) * CAPW + pos] = __uint_as_float(enc);
            }
          }
        }
      }
    }
    sq0 = nsq0; sq1 = nsq1; tj0 = ntj0; tj1 = ntj1;
#pragma unroll
    for (int kb = 0; kb < 4; kb++) { cb0[kb] = nb0[kb]; cb1[kb] = nb1[kb]; }
  }
  __syncthreads();

  // ---- finalize: raw-copy candidate lists (common) or 17-extract (overflow, rare)
  for (int rl = 0; rl < ROWS; rl++) {
    const int c0 = min(cnt[0][rl], CAPW), c1 = min(cnt[1][rl], CAPW),
              c2 = min(cnt[2][rl], CAPW), c3 = min(cnt[3][rl], CAPW);
    const int tot = c0 + c1 + c2 + c3;
    const int grow = rbase + rl;
    float* srow = scr + (size_t)grow * (4 * SEG) + quarter * SEG;
    if (tot <= SEG) {
      const int pre = (w > 0 ? c0 : 0) + (w > 1 ? c1 : 0) + (w > 2 ? c2 : 0);
      const int myc = (w == 0) ? c0 : ((w == 1) ? c1 : ((w == 2) ? c2 : c3));
      if (lane < myc) srow[pre + lane] = sh[(w * ROWS + rl) * CAPW + lane];
      if (tid == 0) cscr[grow * 4 + quarter] = tot;
    } else if (w == (rl & 3)) {
      float e[4]; int m[4];
#pragma unroll
      for (int ww = 0; ww < 4; ww++) {
        int n = min(cnt[ww][rl], CAPW);
        if (lane < n) {
          unsigned u = __float_as_uint(sh[(ww * ROWS + rl) * CAPW + lane]);
          m[ww] = (int)(u >> 31); e[ww] = __uint_as_float(u & 0x7fffffffu);
        } else { e[ww] = BIG; m[ww] = 0; }
      }
      for (int round = 0; round < KSEL; round++) {
        float v = e[0]; int idx = lane;
        if (e[1] < v) { v = e[1]; idx = lane | (1 << 6); }
        if (e[2] < v) { v = e[2]; idx = lane | (2 << 6); }
        if (e[3] < v) { v = e[3]; idx = lane | (3 << 6); }
#pragma unroll
        for (int off = 32; off; off >>= 1) {
          float ov = __shfl_xor(v, off);
          int   oi = __shfl_xor(idx, off);
          if (ov < v || (ov == v && oi < idx)) { v = ov; idx = oi; }
        }
        if ((idx & 63) == lane) {
          int s = idx >> 6;
          unsigned ub = __float_as_uint(e[s]);
          if (m[s]) ub |= 0x80000000u;
          srow[round] = __uint_as_float(ub);
          e[s] = BIG;
        }
      }
      if (lane == 0) cscr[grow * 4 + quarter] = KSEL;
    }
  }
}

// ---- per-row merge of 4 quarter-lists (<=128 candidates) + loss epilogue.
// NO fences, NO global atomics: per-block partials to pacc (plain stores).
__global__ __launch_bounds__(256) void knn_merge(
    const float* __restrict__ scr, const int* __restrict__ cscr,
    const float* __restrict__ sqv, const int* __restrict__ tgt,
    const int* __restrict__ ccount, const int* __restrict__ j0a,
    const int* __restrict__ j1a, const float* __restrict__ X32,
    float* __restrict__ pacc) {
  __shared__ float blockAcc[4];
  const int tid = threadIdx.x;
  const int w = tid >> 6;
  const int lane = tid & 63;
  if (tid < 4) blockAcc[tid] = 0.0f;
  __syncthreads();
  for (int ri = 0; ri < 4; ri++) {
    const int grow = blockIdx.x * 16 + w * 4 + ri;
    const float* srow = scr + (size_t)grow * (4 * SEG);
    const int ca = cscr[grow * 4 + (lane >> 5)];
    const int cb = cscr[grow * 4 + 2 + (lane >> 5)];
    const int li = lane & 31;
    float e0 = BIG, e1 = BIG; int mm0 = 0, mm1 = 0;
    if (li < ca) {
      unsigned u = __float_as_uint(srow[(lane >> 5) * SEG + li]);
      mm0 = (int)(u >> 31); e0 = __uint_as_float(u & 0x7fffffffu);
    }
    if (li < cb) {
      unsigned u = __float_as_uint(srow[(2 + (lane >> 5)) * SEG + li]);
      mm1 = (int)(u >> 31); e1 = __uint_as_float(u & 0x7fffffffu);
    }
    // exact 17th smallest of the union (radix-select)
    const float t17 = kth17_2(e0, e1);
    bool s0 = (e0 < t17), s1 = (e1 < t17);                // strict, matches reference
    float x0 = s0 ? expf(-sqrtf(fmaxf(e0, 1e-12f))) : 0.0f;
    float x1 = s1 ? expf(-sqrtf(fmaxf(e1, 1e-12f))) : 0.0f;
    float pls = (s0 && mm0 ? x0 : 0.0f) + (s1 && mm1 ? x1 : 0.0f);
    float nls = (s0 && !mm0 ? x0 : 0.0f) + (s1 && !mm1 ? x1 : 0.0f);
    int cpn = ((int)(s0 && mm0) + (int)(s1 && mm1)) * 65536 +
              ((int)(s0 && !mm0) + (int)(s1 && !mm1));
#pragma unroll
    for (int off = 32; off; off >>= 1) {
      pls += __shfl_xor(pls, off); nls += __shfl_xor(nls, off);
      cpn += __shfl_xor(cpn, off);
    }
    const int cp = cpn >> 16, cn = cpn & 0xffff;
    const int c = tgt[grow];
    const int ncl = ccount[c];
    const bool valid = (ncl > 1) && (ncl < NPTS);
    if (valid) {
      float pos_eff;
      if (cp == 0) {
        const int jf = (grow == j0a[c]) ? j1a[c] : j0a[c];
        const float* xi = X32 + (size_t)grow * DIM;
        const float* xj = X32 + (size_t)jf * DIM;
        float pp = xi[lane] * xj[lane] + xi[lane + 64] * xj[lane + 64];
#pragma unroll
        for (int off = 32; off; off >>= 1) pp += __shfl_xor(pp, off);
        const float fb2 = sqv[grow] + sqv[jf] - 2.0f * pp;
        pos_eff = expf(-sqrtf(fmaxf(fb2, 1e-12f)));
      } else {
        pos_eff = pls;
      }
      if (lane == 0) {
        const float loss_i = -logf(pos_eff / (pos_eff + nls));
        const int cpa = (cp == 0) ? 1 : cp;
        atomicAdd(&blockAcc[0], loss_i);
        atomicAdd(&blockAcc[1], (cpa > cn) ? 1.0f : 0.0f);
        atomicAdd(&blockAcc[2], (float)cp);
        atomicAdd(&blockAcc[3], (float)cn);
      }
    }
  }
  __syncthreads();
  if (tid < 4) pacc[blockIdx.x * 4 + tid] = blockAcc[tid];
}

// ---- final reduction: 1 block sums 512 x 4 partials, writes out
__global__ void fin(const float* __restrict__ pacc, float* __restrict__ out) {
  __shared__ float red[256];
  const int tid = threadIdx.x;
  const int c = tid & 3, b0 = tid >> 2;
  float s = 0.0f;
  for (int b = b0; b < MBLK; b += 64) s += pacc[b * 4 + c];
  red[tid] = s;
  __syncthreads();
  if (tid < 4) {
    float t = 0.0f;
    for (int i = tid; i < 256; i += 4) t += red[i];
    out[tid] = t * (1.0f / (float)NPTS);
  }
}

extern "C" void kernel_launch(void* const* d_in, const int* in_sizes, int n_in,
                              void* d_out, int out_size, void* d_ws, size_t ws_size,
                              hipStream_t stream) {
  const float* X = (const float*)d_in[0];
  const long long* targets = (const long long*)d_in[1];
  float* out = (float*)d_out;

  char* ws = (char*)d_ws;
  unsigned short* Xb = (unsigned short*)ws;                        // 2 MiB
  float* sqv    = (float*)   (ws + (2u << 20));                    // 32 KiB
  int*   tgt    = (int*)     (ws + (2u << 20) + (32u << 10));      // 32 KiB
  int*   ccount = (int*)     (ws + (2u << 20) + (64u << 10));      // 512 B
  int*   j0a    = (int*)     (ws + (2u << 20) + (65u << 10));      // 512 B
  int*   j1a    = (int*)     (ws + (2u << 20) + (66u << 10));      // 512 B
  float* pacc   = (float*)   (ws + (2u << 20) + (68u << 10));      // 8 KiB (512 x 4)
  float* scr = (float*)(ws + (2u << 20) + (128u << 10));           // 8192*4*SEG*4 = 4 MiB
  int* cscr  = (int*)  (ws + (2u << 20) + (128u << 10) + (size_t)NPTS * 4 * SEG * 4); // 128 KiB

  prep<<<2049, 256, 0, stream>>>(X, targets, Xb, sqv, tgt, ccount, j0a, j1a);
  knn_main<<<1024, 256, 0, stream>>>(Xb, sqv, tgt, scr, cscr);
  knn_merge<<<MBLK, 256, 0, stream>>>(scr, cscr, sqv, tgt, ccount, j0a, j1a, X, pacc);
  fin<<<1, 256, 0, stream>>>(pacc, out);
}

// Round 4
// 187.296 us; speedup vs baseline: 7.3135x; 1.2451x over previous
//
#include <hip/hip_runtime.h>

#define NPTS 8192
#define DIM 128
#define NCLS 128
#define KSEL 17      // k+1 smallest define the threshold
#define RB   64      // rows per block = 4 waves x 16
#define NT8  64      // 16-col tiles per eighth (1024/16)
#define CAPW 40      // per-row LDS candidate capacity
#define SEG  32      // per-(row,eighth) scratch segment
#define NSEG 8       // column eighths
#define MBLK 1024    // merge blocks (8 rows each)
#define BIG 3.0e38f

typedef short bf16x8 __attribute__((ext_vector_type(8)));
typedef float f32x4 __attribute__((ext_vector_type(4)));

__device__ __forceinline__ unsigned short f2bf(float f) {
  unsigned int u = __float_as_uint(f);
  u += 0x7fffu + ((u >> 16) & 1u);   // round-to-nearest-even
  return (unsigned short)(u >> 16);
}

// order-preserving float <-> uint map (total order, exact inverse)
__device__ __forceinline__ unsigned flipF(float f) {
  unsigned u = __float_as_uint(f);
  return (u & 0x80000000u) ? ~u : (u | 0x80000000u);
}
__device__ __forceinline__ float unflipF(unsigned k) {
  unsigned u = (k & 0x80000000u) ? (k & 0x7fffffffu) : ~k;
  return __uint_as_float(u);
}

// exact KSEL-th smallest of the 256 values {a,b,c,d} x 64 lanes.
// all inputs are >= 0 here (encoded d2 with flag stripped, or BIG) ->
// flipped keys all have bit31 set; start descent at bit 30. (proven round-1)
__device__ __forceinline__ float kth17_4(float a, float b, float c, float d) {
  const unsigned ka = flipF(a), kb = flipF(b), kc = flipF(c), kd = flipF(d);
  unsigned ans = 0x80000000u;
  for (int bit = 30; bit >= 0; --bit) {
    unsigned mid = ans | (1u << bit);
    int cc = __popcll(__ballot(ka < mid)) + __popcll(__ballot(kb < mid)) +
             __popcll(__ballot(kc < mid)) + __popcll(__ballot(kd < mid));
    if (cc < KSEL) ans = mid;
  }
  return unflipF(ans);
}

// ---- prep: blocks 0..2047 build bf16 X + exact norms; block 2048: class stats
__global__ void prep(const float* __restrict__ X, const long long* __restrict__ targets,
                     unsigned short* __restrict__ Xb, float* __restrict__ sqv,
                     int* __restrict__ tgt, int* __restrict__ ccount,
                     int* __restrict__ j0a, int* __restrict__ j1a) {
  const int tid = threadIdx.x;
  if (blockIdx.x == 2048) {
    __shared__ int cc[NCLS], c0[NCLS], c1[NCLS];
    if (tid < NCLS) { cc[tid] = 0; c0[tid] = 0x7fffffff; c1[tid] = 0x7fffffff; }
    __syncthreads();
    for (int base = tid * 4; base < NPTS; base += 1024) {
      const long long* p = targets + base;
#pragma unroll
      for (int k = 0; k < 4; k++) {
        int c = (int)p[k];
        tgt[base + k] = c;
        atomicAdd(&cc[c], 1);
        atomicMin(&c0[c], base + k);
      }
    }
    __syncthreads();
    for (int base = tid * 4; base < NPTS; base += 1024) {
#pragma unroll
      for (int k = 0; k < 4; k++) {
        int c = tgt[base + k];
        if (base + k != c0[c]) atomicMin(&c1[c], base + k);
      }
    }
    __syncthreads();
    if (tid < NCLS) { ccount[tid] = cc[tid]; j0a[tid] = c0[tid]; j1a[tid] = c1[tid]; }
    return;
  }
  const int w = tid >> 6, lane = tid & 63;
  const int gw = blockIdx.x * 4 + w;
  const float* xr = X + (size_t)gw * DIM;
  float a = xr[lane], b = xr[lane + 64];
  Xb[(size_t)gw * DIM + lane] = f2bf(a);
  Xb[(size_t)gw * DIM + lane + 64] = f2bf(b);
  float s = a * a + b * b;
#pragma unroll
  for (int off = 32; off; off >>= 1) s += __shfl_xor(s, off);
  if (lane == 0) sqv[gw] = s;
}

// ---- two-sweep kNN, LDS-shared-B structure.
// Block = 64 rows x 1024 cols (one eighth). Wave w owns rows [w*16, w*16+16) —
// one A-set; ALL 4 waves consume the SAME B-tile stream staged in LDS:
//  * per 16-col tile (4KB) each thread reg-stages 16B (coalesced) and writes it
//    to the *other* LDS buffer AFTER the compute phase (T14 issue-early/write-late:
//    global latency hides under MFMA+epilogue), 1 barrier/iteration.
//  * XOR swizzle (byte ^ ((col&7)<<4)) on LDS write+read -> ds_read_b128 of a
//    [16][256B] tile is bank-balanced (8 lanes per 4-bank group = b128 BW floor).
//  * 4x fewer L2 requests than per-wave streaming (tile fetched once per block).
// Row-ownership makes candidate bookkeeping wave-local: ballot+popc append (no
// LDS atomics), counts in registers. Sweep-1 keeps min-4/lane (pool of 64 per
// row -> U = truncated-radix 17th of pool, a tight UPPER bound of the true
// eighth t17; subset property, self masked). val = sqj - 2*G per row.
__global__ __launch_bounds__(256, 4) void knn_main(
    const unsigned short* __restrict__ Xb, const float* __restrict__ sqv,
    const int* __restrict__ tgt, float* __restrict__ scr, int* __restrict__ cscr) {
  __shared__ __align__(16) unsigned short shB[2][2048];  // 8KB B-tile double buffer
  __shared__ __align__(16) float shPub[RB * 64];         // 16KB: min-4 pool, then bufD overlay
  __shared__ int cntL[RB];

  const int tid = threadIdx.x;
  const int w = tid >> 6;
  const int lane = tid & 63;
  const int quad = lane >> 4;
  const int l16 = lane & 15;
  const int rg = blockIdx.x >> 3;
  const int eighth = blockIdx.x & 7;
  const int rbase = rg * RB;
  const int cbase = eighth * 1024;

  // staging constants: thread tid stages bytes [16*tid,16*tid+16) of the 4KB tile;
  // LDS dest byte = (16*tid) ^ ((col&7)<<4), col = tid>>4 (swizzle write side)
  const int swoff = (tid << 4) ^ (((tid >> 4) & 7) << 4);
  const unsigned lmlt = (1u << l16) - 1;
  // ds_read offsets: B[n=l16][k=quad*8+kb*32+j] -> byte l16*256 + quad*16 + kb*64,
  // XOR the same swizzle with col=l16 (read side)
  int rdoff[4];
#pragma unroll
  for (int kb = 0; kb < 4; kb++)
    rdoff[kb] = (l16 * 256 + quad * 16 + kb * 64) ^ ((l16 & 7) << 4);

  // A fragments: wave's 16 rows. 16x16x32 bf16: A[m=l16][k=quad*8+j]
  bf16x8 afrag[4];
  {
    const unsigned short* arow = Xb + (size_t)(rbase + w * 16 + l16) * DIM + quad * 8;
#pragma unroll
    for (int kb = 0; kb < 4; kb++) afrag[kb] = *(const bf16x8*)(arow + kb * 32);
  }
  float sqi[4]; int ti[4];
#pragma unroll
  for (int r = 0; r < 4; r++) {
    int rr = rbase + w * 16 + quad * 4 + r;
    sqi[r] = sqv[rr]; ti[r] = tgt[rr];
  }
  // wave-uniform diagonal tile (rows are 16-aligned -> at t==tdw, self col has
  // in-tile index quad*4+r, i.e. mask lane l16 == quad*4+r)
  int tdw;
  {
    int d = rbase + w * 16 - cbase;
    tdw = (d >= 0 && d < 1024) ? (d >> 4) : -1;
  }

  const unsigned short* gtile0 = Xb + (size_t)cbase * DIM;
  const float* sqp = sqv + cbase + l16;
  const int*   tgp = tgt + cbase + l16;

  // ---- sweep 1: min-4 per (row, l16-class)
  float m1[4], m2[4], m3[4], m4[4];
#pragma unroll
  for (int r = 0; r < 4; r++) { m1[r] = BIG; m2[r] = BIG; m3[r] = BIG; m4[r] = BIG; }
  {
    bf16x8 s0 = *(const bf16x8*)(gtile0 + tid * 8);
    *(bf16x8*)((char*)&shB[0][0] + swoff) = s0;
  }
  float sqc = sqp[0];
  __syncthreads();
  for (int t = 0; t < NT8; t++) {
    const int tn = (t + 1) & (NT8 - 1);
    bf16x8 stg = *(const bf16x8*)(gtile0 + (size_t)tn * 2048 + tid * 8);
    const float sqn = sqp[tn * 16];
    const char* lb = (const char*)&shB[t & 1][0];
    bf16x8 b[4];
#pragma unroll
    for (int kb = 0; kb < 4; kb++) b[kb] = *(const bf16x8*)(lb + rdoff[kb]);
    f32x4 acc = {0.f, 0.f, 0.f, 0.f};
#pragma unroll
    for (int kb = 0; kb < 4; kb++)
      acc = __builtin_amdgcn_mfma_f32_16x16x32_bf16(afrag[kb], b[kb], acc, 0, 0, 0);
    float v[4];
#pragma unroll
    for (int r = 0; r < 4; r++) v[r] = fmaf(-2.0f, acc[r], sqc);
    if (t == tdw) {
#pragma unroll
      for (int r = 0; r < 4; r++) if (l16 == quad * 4 + r) v[r] = BIG;
    }
#pragma unroll
    for (int r = 0; r < 4; r++) {
      m4[r] = fminf(m4[r], fmaxf(m3[r], v[r]));
      m3[r] = fminf(m3[r], fmaxf(m2[r], v[r]));
      m2[r] = fminf(m2[r], fmaxf(m1[r], v[r]));
      m1[r] = fminf(m1[r], v[r]);
    }
    sqc = sqn;
    *(bf16x8*)((char*)&shB[(t & 1) ^ 1][0] + swoff) = stg;   // write-late (T14)
    __syncthreads();
  }

  // ---- U[row]: publish min-4 pool (64 values/row), truncated radix-select.
  // Truncation at bit 14 + low-ones fill gives U >= true 17th (upper bound, safe).
#pragma unroll
  for (int r = 0; r < 4; r++) {
    f32x4 mq = {m1[r], m2[r], m3[r], m4[r]};
    *(f32x4*)&shPub[(w * 16 + quad * 4 + r) * 64 + l16 * 4] = mq;
  }
  __syncthreads();
  float Ur[4] = {0.f, 0.f, 0.f, 0.f};
  for (int rp = 0; rp < 16; rp += 2) {   // two rows interleaved (fills ballot stalls)
    const unsigned ka = flipF(shPub[(w * 16 + rp) * 64 + lane]);
    const unsigned kb2 = flipF(shPub[(w * 16 + rp + 1) * 64 + lane]);
    unsigned ansA = 0u, ansB = 0u;
    for (int bit = 31; bit >= 14; --bit) {
      const unsigned mA = ansA | (1u << bit), mB = ansB | (1u << bit);
      const int ca = __popcll(__ballot(ka < mA));
      const int cb = __popcll(__ballot(kb2 < mB));
      if (ca < KSEL) ansA = mA;
      if (cb < KSEL) ansB = mB;
    }
    const float ua = unflipF(ansA | 0x3FFFu), ub = unflipF(ansB | 0x3FFFu);
#pragma unroll
    for (int r = 0; r < 4; r++) {
      const int myrow = quad * 4 + r;
      if (myrow == rp) Ur[r] = ua;
      if (myrow == rp + 1) Ur[r] = ub;
    }
  }

  // ---- sweep 2: append val <= U (encode d2 = val + sqi, flag in sign bit).
  // bufD overlays shPub (disjoint phases; the prologue barrier orders them).
  float* bufD = shPub;
  int cntr[4] = {0, 0, 0, 0};
  {
    bf16x8 s0 = *(const bf16x8*)(gtile0 + tid * 8);
    *(bf16x8*)((char*)&shB[0][0] + swoff) = s0;
  }
  sqc = sqp[0];
  int tjc = tgp[0];
  __syncthreads();
  for (int t = 0; t < NT8; t++) {
    const int tn = (t + 1) & (NT8 - 1);
    bf16x8 stg = *(const bf16x8*)(gtile0 + (size_t)tn * 2048 + tid * 8);
    const float sqn = sqp[tn * 16];
    const int tjn = tgp[tn * 16];
    const char* lb = (const char*)&shB[t & 1][0];
    bf16x8 b[4];
#pragma unroll
    for (int kb = 0; kb < 4; kb++) b[kb] = *(const bf16x8*)(lb + rdoff[kb]);
    f32x4 acc = {0.f, 0.f, 0.f, 0.f};
#pragma unroll
    for (int kb = 0; kb < 4; kb++)
      acc = __builtin_amdgcn_mfma_f32_16x16x32_bf16(afrag[kb], b[kb], acc, 0, 0, 0);
    float v[4];
#pragma unroll
    for (int r = 0; r < 4; r++) v[r] = fmaf(-2.0f, acc[r], sqc);
    if (t == tdw) {
#pragma unroll
      for (int r = 0; r < 4; r++) if (l16 == quad * 4 + r) v[r] = BIG;
    }
#pragma unroll
    for (int r = 0; r < 4; r++) {
      const bool pred = (v[r] <= Ur[r]);
      const unsigned long long bal = __ballot(pred);
      if (bal) {
        const unsigned qm = (unsigned)(bal >> (quad << 4)) & 0xFFFFu;
        const int pos = cntr[r] + __popc(qm & lmlt);
        if (pred && pos < CAPW) {
          unsigned enc = __float_as_uint(fmaxf(v[r] + sqi[r], 0.0f));
          if (tjc == ti[r]) enc |= 0x80000000u;
          bufD[(w * 16 + quad * 4 + r) * CAPW + pos] = __uint_as_float(enc);
        }
        cntr[r] += __popc(qm);   // identical across the quad's 16 lanes
      }
    }
    sqc = sqn; tjc = tjn;
    *(bf16x8*)((char*)&shB[(t & 1) ^ 1][0] + swoff) = stg;
    __syncthreads();
  }
#pragma unroll
  for (int r = 0; r < 4; r++)
    if (l16 == 0) cntL[w * 16 + quad * 4 + r] = cntr[r];
  __syncthreads();

  // ---- finalize (wave-local rows): raw copy (common) or exact 17-extract (rare)
  for (int rl = 0; rl < 16; rl++) {
    const int grow = rbase + w * 16 + rl;
    const int tot = cntL[w * 16 + rl];
    float* srow = scr + (size_t)grow * (NSEG * SEG) + eighth * SEG;
    if (tot <= SEG) {
      if (lane < tot) srow[lane] = bufD[(w * 16 + rl) * CAPW + lane];
      if (lane == 0) cscr[grow * NSEG + eighth] = tot;
    } else {
      const int n = min(tot, CAPW);
      float e = BIG; int m = 0;
      if (lane < n) {
        unsigned u = __float_as_uint(bufD[(w * 16 + rl) * CAPW + lane]);
        m = (int)(u >> 31); e = __uint_as_float(u & 0x7fffffffu);
      }
      for (int round = 0; round < KSEL; round++) {
        float vv = e; int idx = lane;
#pragma unroll
        for (int off = 32; off; off >>= 1) {
          float ov = __shfl_xor(vv, off);
          int   oi = __shfl_xor(idx, off);
          if (ov < vv || (ov == vv && oi < idx)) { vv = ov; idx = oi; }
        }
        if (idx == lane) {
          unsigned ub = __float_as_uint(e);
          if (m) ub |= 0x80000000u;
          srow[round] = __uint_as_float(ub);
          e = BIG;
        }
      }
      if (lane == 0) cscr[grow * NSEG + eighth] = KSEL;
    }
  }
}

// ---- per-row merge of 8 segment-lists (<=256 candidates, 4 per lane) + loss epilogue.
// (verbatim from round-1 run: passed, absmax 0.03125)
__global__ __launch_bounds__(256) void knn_merge(
    const float* __restrict__ scr, const int* __restrict__ cscr,
    const float* __restrict__ sqv, const int* __restrict__ tgt,
    const int* __restrict__ ccount, const int* __restrict__ j0a,
    const int* __restrict__ j1a, const float* __restrict__ X32,
    float* __restrict__ pacc) {
  __shared__ float blockAcc[4];
  const int tid = threadIdx.x;
  const int w = tid >> 6;
  const int lane = tid & 63;
  if (tid < 4) blockAcc[tid] = 0.0f;
  __syncthreads();
  for (int ri = 0; ri < 2; ri++) {
    const int grow = blockIdx.x * 8 + w * 2 + ri;
    const float* srow = scr + (size_t)grow * (NSEG * SEG);
    const int h = lane >> 5, li = lane & 31;
    float e[4]; int mm[4];
#pragma unroll
    for (int j = 0; j < 4; j++) {
      const int seg = j * 2 + h;
      const int cj = cscr[grow * NSEG + seg];
      if (li < cj) {
        unsigned u = __float_as_uint(srow[seg * SEG + li]);
        mm[j] = (int)(u >> 31); e[j] = __uint_as_float(u & 0x7fffffffu);
      } else { e[j] = BIG; mm[j] = 0; }
    }
    const float t17 = kth17_4(e[0], e[1], e[2], e[3]);
    float pls = 0.0f, nls = 0.0f; int cp = 0, cn = 0;
#pragma unroll
    for (int j = 0; j < 4; j++) {
      const bool s = (e[j] < t17);                        // strict, matches reference
      const float x = s ? expf(-sqrtf(fmaxf(e[j], 1e-12f))) : 0.0f;
      if (mm[j]) { pls += x; cp += (int)s; }
      else       { nls += x; cn += (int)s; }
    }
    int cpn = cp * 65536 + cn;
#pragma unroll
    for (int off = 32; off; off >>= 1) {
      pls += __shfl_xor(pls, off); nls += __shfl_xor(nls, off);
      cpn += __shfl_xor(cpn, off);
    }
    const int cpt = cpn >> 16, cnt_ = cpn & 0xffff;
    const int c = tgt[grow];
    const int ncl = ccount[c];
    const bool valid = (ncl > 1) && (ncl < NPTS);
    if (valid) {
      float pos_eff;
      if (cpt == 0) {
        const int jf = (grow == j0a[c]) ? j1a[c] : j0a[c];
        const float* xi = X32 + (size_t)grow * DIM;
        const float* xj = X32 + (size_t)jf * DIM;
        float pp = xi[lane] * xj[lane] + xi[lane + 64] * xj[lane + 64];
#pragma unroll
        for (int off = 32; off; off >>= 1) pp += __shfl_xor(pp, off);
        const float fb2 = sqv[grow] + sqv[jf] - 2.0f * pp;
        pos_eff = expf(-sqrtf(fmaxf(fb2, 1e-12f)));
      } else {
        pos_eff = pls;
      }
      if (lane == 0) {
        const float loss_i = -logf(pos_eff / (pos_eff + nls));
        const int cpa = (cpt == 0) ? 1 : cpt;
        atomicAdd(&blockAcc[0], loss_i);
        atomicAdd(&blockAcc[1], (cpa > cnt_) ? 1.0f : 0.0f);
        atomicAdd(&blockAcc[2], (float)cpt);
        atomicAdd(&blockAcc[3], (float)cnt_);
      }
    }
  }
  __syncthreads();
  if (tid < 4) pacc[blockIdx.x * 4 + tid] = blockAcc[tid];
}

// ---- final reduction: 1 block sums 1024 x 4 partials, writes out
__global__ void fin(const float* __restrict__ pacc, float* __restrict__ out) {
  __shared__ float red[256];
  const int tid = threadIdx.x;
  const int c = tid & 3, b0 = tid >> 2;
  float s = 0.0f;
  for (int b = b0; b < MBLK; b += 64) s += pacc[b * 4 + c];
  red[tid] = s;
  __syncthreads();
  if (tid < 4) {
    float t = 0.0f;
    for (int i = tid; i < 256; i += 4) t += red[i];
    out[tid] = t * (1.0f / (float)NPTS);
  }
}

extern "C" void kernel_launch(void* const* d_in, const int* in_sizes, int n_in,
                              void* d_out, int out_size, void* d_ws, size_t ws_size,
                              hipStream_t stream) {
  const float* X = (const float*)d_in[0];
  const long long* targets = (const long long*)d_in[1];
  float* out = (float*)d_out;

  char* ws = (char*)d_ws;
  unsigned short* Xb = (unsigned short*)ws;                        // 2 MiB
  float* sqv    = (float*)   (ws + (2u << 20));                    // 32 KiB
  int*   tgt    = (int*)     (ws + (2u << 20) + (32u << 10));      // 32 KiB
  int*   ccount = (int*)     (ws + (2u << 20) + (64u << 10));      // 512 B
  int*   j0a    = (int*)     (ws + (2u << 20) + (65u << 10));      // 512 B
  int*   j1a    = (int*)     (ws + (2u << 20) + (66u << 10));      // 512 B
  float* pacc   = (float*)   (ws + (2u << 20) + (68u << 10));      // 16 KiB (1024 x 4)
  float* scr = (float*)(ws + (2u << 20) + (128u << 10));           // 8192*8*SEG*4 = 8 MiB
  int* cscr  = (int*)  (ws + (2u << 20) + (128u << 10) +
                        (size_t)NPTS * NSEG * SEG * 4);            // 256 KiB

  prep<<<2049, 256, 0, stream>>>(X, targets, Xb, sqv, tgt, ccount, j0a, j1a);
  knn_main<<<1024, 256, 0, stream>>>(Xb, sqv, tgt, scr, cscr);
  knn_merge<<<MBLK, 256, 0, stream>>>(scr, cscr, sqv, tgt, ccount, j0a, j1a, X, pacc);
  fin<<<1, 256, 0, stream>>>(pacc, out);
}

// Round 5
// 174.104 us; speedup vs baseline: 7.8677x; 1.0758x over previous
//
#include <hip/hip_runtime.h>

#define NPTS 8192
#define DIM 128
#define NCLS 128
#define KSEL 17      // k+1 smallest define the threshold
#define RB   64      // rows per block = 4 waves x 16
#define NIT  32      // 32-col steps per eighth (1024/32)
#define CAPW 40      // per-row LDS candidate capacity
#define SEG  32      // per-(row,eighth) scratch segment
#define NSEG 8       // column eighths
#define MBLK 1024    // merge blocks (8 rows each)
#define BIG 3.0e38f

typedef short bf16x8 __attribute__((ext_vector_type(8)));
typedef float f32x4 __attribute__((ext_vector_type(4)));

__device__ __forceinline__ unsigned short f2bf(float f) {
  unsigned int u = __float_as_uint(f);
  u += 0x7fffu + ((u >> 16) & 1u);   // round-to-nearest-even
  return (unsigned short)(u >> 16);
}

// order-preserving float <-> uint map (total order, exact inverse)
__device__ __forceinline__ unsigned flipF(float f) {
  unsigned u = __float_as_uint(f);
  return (u & 0x80000000u) ? ~u : (u | 0x80000000u);
}
__device__ __forceinline__ float unflipF(unsigned k) {
  unsigned u = (k & 0x80000000u) ? (k & 0x7fffffffu) : ~k;
  return __uint_as_float(u);
}

// exact KSEL-th smallest of the 256 values {a,b,c,d} x 64 lanes.
// all inputs are >= 0 here (encoded d2 with flag stripped, or BIG) ->
// flipped keys all have bit31 set; start descent at bit 30. (proven round-1/4)
__device__ __forceinline__ float kth17_4(float a, float b, float c, float d) {
  const unsigned ka = flipF(a), kb = flipF(b), kc = flipF(c), kd = flipF(d);
  unsigned ans = 0x80000000u;
  for (int bit = 30; bit >= 0; --bit) {
    unsigned mid = ans | (1u << bit);
    int cc = __popcll(__ballot(ka < mid)) + __popcll(__ballot(kb < mid)) +
             __popcll(__ballot(kc < mid)) + __popcll(__ballot(kd < mid));
    if (cc < KSEL) ans = mid;
  }
  return unflipF(ans);
}

// ---- prep: blocks 0..2047 build bf16 X + exact norms; block 2048: class stats
__global__ void prep(const float* __restrict__ X, const long long* __restrict__ targets,
                     unsigned short* __restrict__ Xb, float* __restrict__ sqv,
                     int* __restrict__ tgt, int* __restrict__ ccount,
                     int* __restrict__ j0a, int* __restrict__ j1a) {
  const int tid = threadIdx.x;
  if (blockIdx.x == 2048) {
    __shared__ int cc[NCLS], c0[NCLS], c1[NCLS];
    if (tid < NCLS) { cc[tid] = 0; c0[tid] = 0x7fffffff; c1[tid] = 0x7fffffff; }
    __syncthreads();
    for (int base = tid * 4; base < NPTS; base += 1024) {
      const long long* p = targets + base;
#pragma unroll
      for (int k = 0; k < 4; k++) {
        int c = (int)p[k];
        tgt[base + k] = c;
        atomicAdd(&cc[c], 1);
        atomicMin(&c0[c], base + k);
      }
    }
    __syncthreads();
    for (int base = tid * 4; base < NPTS; base += 1024) {
#pragma unroll
      for (int k = 0; k < 4; k++) {
        int c = tgt[base + k];
        if (base + k != c0[c]) atomicMin(&c1[c], base + k);
      }
    }
    __syncthreads();
    if (tid < NCLS) { ccount[tid] = cc[tid]; j0a[tid] = c0[tid]; j1a[tid] = c1[tid]; }
    return;
  }
  const int w = tid >> 6, lane = tid & 63;
  const int gw = blockIdx.x * 4 + w;
  const float* xr = X + (size_t)gw * DIM;
  float a = xr[lane], b = xr[lane + 64];
  Xb[(size_t)gw * DIM + lane] = f2bf(a);
  Xb[(size_t)gw * DIM + lane + 64] = f2bf(b);
  float s = a * a + b * b;
#pragma unroll
  for (int off = 32; off; off >>= 1) s += __shfl_xor(s, off);
  if (lane == 0) sqv[gw] = s;
}

// ---- two-sweep kNN, LDS-shared-B, 32-col steps (2 MFMA tiles per stage).
// Block = 64 rows x 1024 cols (one eighth). Wave w owns rows [w*16, w*16+16);
// all 4 waves consume the same 32-col B-slab (8KB) staged in a double-buffered
// LDS (write-late / T14). vs round-4 (16-col steps): barriers 128->64 per block,
// loop/rotate/staging fixed costs halved; per-element math unchanged. Sweep-1
// tracks min-2/lane (pool 32/row >= KSEL; U = truncated-radix 17th of pool, an
// upper bound of the eighth's true 17th — subset property, self masked).
// XOR swizzle byte^((col&7)<<4) on LDS write+read keeps ds b128 at the bank floor.
// val = sqj - 2*G per row (sqi-invariant ordering).
__global__ __launch_bounds__(256, 4) void knn_main(
    const unsigned short* __restrict__ Xb, const float* __restrict__ sqv,
    const int* __restrict__ tgt, float* __restrict__ scr, int* __restrict__ cscr) {
  __shared__ __align__(16) unsigned short shB[2][4096];  // 2 x 8KB B-slab double buffer
  __shared__ __align__(16) float shPub[RB * CAPW];       // 10KB: min-2 pool (8KB) / bufD overlay
  __shared__ int cntL[RB];

  const int tid = threadIdx.x;
  const int w = tid >> 6;
  const int lane = tid & 63;
  const int quad = lane >> 4;
  const int l16 = lane & 15;
  const int rg = blockIdx.x >> 3;
  const int eighth = blockIdx.x & 7;
  const int rbase = rg * RB;
  const int cbase = eighth * 1024;

  // staging: thread tid stages bytes [32*tid, 32*tid+32) of the 8KB slab
  // (two b128 writes). col = tid>>3; dest byte = src ^ ((col&7)<<4); the +16
  // half differs only in bit4 -> dest1 = dest0 ^ 16.
  const int w0off = (tid << 5) ^ (((tid >> 3) & 7) << 4);
  const unsigned lmlt = (1u << l16) - 1;
  // ds_read: B[col=l16(+16)][k=quad*8+kb*32+j] -> byte l16*256+quad*16+kb*64 (tile1:+4096),
  // XOR the same swizzle (col&7 = l16&7 for both tiles)
  int rdoff[4];
#pragma unroll
  for (int kb = 0; kb < 4; kb++)
    rdoff[kb] = (l16 * 256 + quad * 16 + kb * 64) ^ ((l16 & 7) << 4);

  // A fragments: wave's 16 rows. 16x16x32 bf16: A[m=l16][k=quad*8+j]
  bf16x8 afrag[4];
  {
    const unsigned short* arow = Xb + (size_t)(rbase + w * 16 + l16) * DIM + quad * 8;
#pragma unroll
    for (int kb = 0; kb < 4; kb++) afrag[kb] = *(const bf16x8*)(arow + kb * 32);
  }
  float sqi[4]; int ti[4];
#pragma unroll
  for (int r = 0; r < 4; r++) {
    int rr = rbase + w * 16 + quad * 4 + r;
    sqi[r] = sqv[rr]; ti[r] = tgt[rr];
  }
  // wave-uniform diagonal 16-col tile index (0..63) or -1
  int tdw;
  {
    int d = rbase + w * 16 - cbase;
    tdw = (d >= 0 && d < 1024) ? (d >> 4) : -1;
  }

  const unsigned short* gtile0 = Xb + (size_t)cbase * DIM;
  const float* sqp = sqv + cbase + l16;
  const int*   tgp = tgt + cbase + l16;

  // ---- sweep 1: min-2 per (row, l16-class); 32 cols per stage
  float m1[4], m2[4];
#pragma unroll
  for (int r = 0; r < 4; r++) { m1[r] = BIG; m2[r] = BIG; }
  {
    bf16x8 s0 = *(const bf16x8*)(gtile0 + tid * 16);
    bf16x8 s1 = *(const bf16x8*)(gtile0 + tid * 16 + 8);
    *(bf16x8*)((char*)&shB[0][0] + w0off) = s0;
    *(bf16x8*)((char*)&shB[0][0] + (w0off ^ 16)) = s1;
  }
  float sq0 = sqp[0], sq1 = sqp[16];
  __syncthreads();
  for (int j = 0; j < NIT; j++) {
    const int jn = (j + 1) & (NIT - 1);
    const unsigned short* src = gtile0 + (size_t)jn * 4096;
    bf16x8 s0 = *(const bf16x8*)(src + tid * 16);
    bf16x8 s1 = *(const bf16x8*)(src + tid * 16 + 8);
    const float nsq0 = sqp[jn * 32], nsq1 = sqp[jn * 32 + 16];
    const char* lb = (const char*)&shB[j & 1][0];
    bf16x8 b0[4], b1[4];
#pragma unroll
    for (int kb = 0; kb < 4; kb++) {
      b0[kb] = *(const bf16x8*)(lb + rdoff[kb]);
      b1[kb] = *(const bf16x8*)(lb + rdoff[kb] + 4096);
    }
    f32x4 a0 = {0.f, 0.f, 0.f, 0.f}, a1 = {0.f, 0.f, 0.f, 0.f};
#pragma unroll
    for (int kb = 0; kb < 4; kb++) {
      a0 = __builtin_amdgcn_mfma_f32_16x16x32_bf16(afrag[kb], b0[kb], a0, 0, 0, 0);
      a1 = __builtin_amdgcn_mfma_f32_16x16x32_bf16(afrag[kb], b1[kb], a1, 0, 0, 0);
    }
    float v0[4], v1[4];
#pragma unroll
    for (int r = 0; r < 4; r++) {
      v0[r] = fmaf(-2.0f, a0[r], sq0);
      v1[r] = fmaf(-2.0f, a1[r], sq1);
    }
    if ((unsigned)(tdw - 2 * j) < 2u) {
#pragma unroll
      for (int r = 0; r < 4; r++) {
        if (2 * j == tdw && l16 == quad * 4 + r) v0[r] = BIG;
        if (2 * j + 1 == tdw && l16 == quad * 4 + r) v1[r] = BIG;
      }
    }
#pragma unroll
    for (int r = 0; r < 4; r++) {
      m2[r] = fminf(m2[r], fmaxf(m1[r], v0[r]));
      m1[r] = fminf(m1[r], v0[r]);
      m2[r] = fminf(m2[r], fmaxf(m1[r], v1[r]));
      m1[r] = fminf(m1[r], v1[r]);
    }
    sq0 = nsq0; sq1 = nsq1;
    char* wb = (char*)&shB[(j & 1) ^ 1][0];
    *(bf16x8*)(wb + w0off) = s0;                 // write-late (T14)
    *(bf16x8*)(wb + (w0off ^ 16)) = s1;
    __syncthreads();
  }

  // ---- U[row]: publish min-2 pool (32 values/row), truncated radix-select.
  // Truncation at bit 14 + low-ones fill gives U >= true 17th (upper bound, safe).
#pragma unroll
  for (int r = 0; r < 4; r++) {
    const int row = w * 16 + quad * 4 + r;
    shPub[row * 32 + l16 * 2] = m1[r];
    shPub[row * 32 + l16 * 2 + 1] = m2[r];
  }
  __syncthreads();
  float Ur[4] = {0.f, 0.f, 0.f, 0.f};
  for (int rp = 0; rp < 16; rp += 2) {   // two rows interleaved (fills ballot stalls)
    const int li = lane & 31;
    const unsigned ka = (lane < 32) ? flipF(shPub[(w * 16 + rp) * 32 + li]) : 0xFFFFFFFFu;
    const unsigned kb2 = (lane < 32) ? flipF(shPub[(w * 16 + rp + 1) * 32 + li]) : 0xFFFFFFFFu;
    unsigned ansA = 0u, ansB = 0u;
    for (int bit = 31; bit >= 14; --bit) {
      const unsigned mA = ansA | (1u << bit), mB = ansB | (1u << bit);
      const int ca = __popcll(__ballot(ka < mA));
      const int cb = __popcll(__ballot(kb2 < mB));
      if (ca < KSEL) ansA = mA;
      if (cb < KSEL) ansB = mB;
    }
    const float ua = unflipF(ansA | 0x3FFFu), ub = unflipF(ansB | 0x3FFFu);
#pragma unroll
    for (int r = 0; r < 4; r++) {
      const int myrow = quad * 4 + r;
      if (myrow == rp) Ur[r] = ua;
      if (myrow == rp + 1) Ur[r] = ub;
    }
  }

  // ---- sweep 2: append val <= U (encode d2 = val + sqi, flag in sign bit).
  // bufD overlays shPub (disjoint phases; the prologue barrier orders them).
  float* bufD = shPub;
  int cntr[4] = {0, 0, 0, 0};
  {
    bf16x8 s0 = *(const bf16x8*)(gtile0 + tid * 16);
    bf16x8 s1 = *(const bf16x8*)(gtile0 + tid * 16 + 8);
    *(bf16x8*)((char*)&shB[0][0] + w0off) = s0;
    *(bf16x8*)((char*)&shB[0][0] + (w0off ^ 16)) = s1;
  }
  sq0 = sqp[0]; sq1 = sqp[16];
  int tj0 = tgp[0], tj1 = tgp[16];
  __syncthreads();
  for (int j = 0; j < NIT; j++) {
    const int jn = (j + 1) & (NIT - 1);
    const unsigned short* src = gtile0 + (size_t)jn * 4096;
    bf16x8 s0 = *(const bf16x8*)(src + tid * 16);
    bf16x8 s1 = *(const bf16x8*)(src + tid * 16 + 8);
    const float nsq0 = sqp[jn * 32], nsq1 = sqp[jn * 32 + 16];
    const int ntj0 = tgp[jn * 32], ntj1 = tgp[jn * 32 + 16];
    const char* lb = (const char*)&shB[j & 1][0];
    bf16x8 b0[4], b1[4];
#pragma unroll
    for (int kb = 0; kb < 4; kb++) {
      b0[kb] = *(const bf16x8*)(lb + rdoff[kb]);
      b1[kb] = *(const bf16x8*)(lb + rdoff[kb] + 4096);
    }
    f32x4 a0 = {0.f, 0.f, 0.f, 0.f}, a1 = {0.f, 0.f, 0.f, 0.f};
#pragma unroll
    for (int kb = 0; kb < 4; kb++) {
      a0 = __builtin_amdgcn_mfma_f32_16x16x32_bf16(afrag[kb], b0[kb], a0, 0, 0, 0);
      a1 = __builtin_amdgcn_mfma_f32_16x16x32_bf16(afrag[kb], b1[kb], a1, 0, 0, 0);
    }
    float v0[4], v1[4];
#pragma unroll
    for (int r = 0; r < 4; r++) {
      v0[r] = fmaf(-2.0f, a0[r], sq0);
      v1[r] = fmaf(-2.0f, a1[r], sq1);
    }
    if ((unsigned)(tdw - 2 * j) < 2u) {
#pragma unroll
      for (int r = 0; r < 4; r++) {
        if (2 * j == tdw && l16 == quad * 4 + r) v0[r] = BIG;
        if (2 * j + 1 == tdw && l16 == quad * 4 + r) v1[r] = BIG;
      }
    }
#pragma unroll
    for (int r = 0; r < 4; r++) {
      {
        const bool p = (v0[r] <= Ur[r]);
        const unsigned long long bal = __ballot(p);
        if (bal) {
          const unsigned qm = (unsigned)(bal >> (quad << 4)) & 0xFFFFu;
          const int pos = cntr[r] + __popc(qm & lmlt);
          if (p && pos < CAPW) {
            unsigned enc = __float_as_uint(fmaxf(v0[r] + sqi[r], 0.0f));
            if (tj0 == ti[r]) enc |= 0x80000000u;
            bufD[(w * 16 + quad * 4 + r) * CAPW + pos] = __uint_as_float(enc);
          }
          cntr[r] += __popc(qm);   // identical across the quad's 16 lanes
        }
      }
      {
        const bool p = (v1[r] <= Ur[r]);
        const unsigned long long bal = __ballot(p);
        if (bal) {
          const unsigned qm = (unsigned)(bal >> (quad << 4)) & 0xFFFFu;
          const int pos = cntr[r] + __popc(qm & lmlt);
          if (p && pos < CAPW) {
            unsigned enc = __float_as_uint(fmaxf(v1[r] + sqi[r], 0.0f));
            if (tj1 == ti[r]) enc |= 0x80000000u;
            bufD[(w * 16 + quad * 4 + r) * CAPW + pos] = __uint_as_float(enc);
          }
          cntr[r] += __popc(qm);
        }
      }
    }
    sq0 = nsq0; sq1 = nsq1; tj0 = ntj0; tj1 = ntj1;
    char* wb = (char*)&shB[(j & 1) ^ 1][0];
    *(bf16x8*)(wb + w0off) = s0;
    *(bf16x8*)(wb + (w0off ^ 16)) = s1;
    __syncthreads();
  }
#pragma unroll
  for (int r = 0; r < 4; r++)
    if (l16 == 0) cntL[w * 16 + quad * 4 + r] = cntr[r];
  __syncthreads();

  // ---- finalize (wave-local rows): raw copy (common) or exact 17-extract (rare)
  for (int rl = 0; rl < 16; rl++) {
    const int grow = rbase + w * 16 + rl;
    const int tot = cntL[w * 16 + rl];
    float* srow = scr + (size_t)grow * (NSEG * SEG) + eighth * SEG;
    if (tot <= SEG) {
      if (lane < tot) srow[lane] = bufD[(w * 16 + rl) * CAPW + lane];
      if (lane == 0) cscr[grow * NSEG + eighth] = tot;
    } else {
      const int n = min(tot, CAPW);
      float e = BIG; int m = 0;
      if (lane < n) {
        unsigned u = __float_as_uint(bufD[(w * 16 + rl) * CAPW + lane]);
        m = (int)(u >> 31); e = __uint_as_float(u & 0x7fffffffu);
      }
      for (int round = 0; round < KSEL; round++) {
        float vv = e; int idx = lane;
#pragma unroll
        for (int off = 32; off; off >>= 1) {
          float ov = __shfl_xor(vv, off);
          int   oi = __shfl_xor(idx, off);
          if (ov < vv || (ov == vv && oi < idx)) { vv = ov; idx = oi; }
        }
        if (idx == lane) {
          unsigned ub = __float_as_uint(e);
          if (m) ub |= 0x80000000u;
          srow[round] = __uint_as_float(ub);
          e = BIG;
        }
      }
      if (lane == 0) cscr[grow * NSEG + eighth] = KSEL;
    }
  }
}

// ---- per-row merge of 8 segment-lists (<=256 candidates, 4 per lane) + loss epilogue.
// (verbatim from round-1/4 runs: passed, absmax 0.03125)
__global__ __launch_bounds__(256) void knn_merge(
    const float* __restrict__ scr, const int* __restrict__ cscr,
    const float* __restrict__ sqv, const int* __restrict__ tgt,
    const int* __restrict__ ccount, const int* __restrict__ j0a,
    const int* __restrict__ j1a, const float* __restrict__ X32,
    float* __restrict__ pacc) {
  __shared__ float blockAcc[4];
  const int tid = threadIdx.x;
  const int w = tid >> 6;
  const int lane = tid & 63;
  if (tid < 4) blockAcc[tid] = 0.0f;
  __syncthreads();
  for (int ri = 0; ri < 2; ri++) {
    const int grow = blockIdx.x * 8 + w * 2 + ri;
    const float* srow = scr + (size_t)grow * (NSEG * SEG);
    const int h = lane >> 5, li = lane & 31;
    float e[4]; int mm[4];
#pragma unroll
    for (int j = 0; j < 4; j++) {
      const int seg = j * 2 + h;
      const int cj = cscr[grow * NSEG + seg];
      if (li < cj) {
        unsigned u = __float_as_uint(srow[seg * SEG + li]);
        mm[j] = (int)(u >> 31); e[j] = __uint_as_float(u & 0x7fffffffu);
      } else { e[j] = BIG; mm[j] = 0; }
    }
    const float t17 = kth17_4(e[0], e[1], e[2], e[3]);
    float pls = 0.0f, nls = 0.0f; int cp = 0, cn = 0;
#pragma unroll
    for (int j = 0; j < 4; j++) {
      const bool s = (e[j] < t17);                        // strict, matches reference
      const float x = s ? expf(-sqrtf(fmaxf(e[j], 1e-12f))) : 0.0f;
      if (mm[j]) { pls += x; cp += (int)s; }
      else       { nls += x; cn += (int)s; }
    }
    int cpn = cp * 65536 + cn;
#pragma unroll
    for (int off = 32; off; off >>= 1) {
      pls += __shfl_xor(pls, off); nls += __shfl_xor(nls, off);
      cpn += __shfl_xor(cpn, off);
    }
    const int cpt = cpn >> 16, cnt_ = cpn & 0xffff;
    const int c = tgt[grow];
    const int ncl = ccount[c];
    const bool valid = (ncl > 1) && (ncl < NPTS);
    if (valid) {
      float pos_eff;
      if (cpt == 0) {
        const int jf = (grow == j0a[c]) ? j1a[c] : j0a[c];
        const float* xi = X32 + (size_t)grow * DIM;
        const float* xj = X32 + (size_t)jf * DIM;
        float pp = xi[lane] * xj[lane] + xi[lane + 64] * xj[lane + 64];
#pragma unroll
        for (int off = 32; off; off >>= 1) pp += __shfl_xor(pp, off);
        const float fb2 = sqv[grow] + sqv[jf] - 2.0f * pp;
        pos_eff = expf(-sqrtf(fmaxf(fb2, 1e-12f)));
      } else {
        pos_eff = pls;
      }
      if (lane == 0) {
        const float loss_i = -logf(pos_eff / (pos_eff + nls));
        const int cpa = (cpt == 0) ? 1 : cpt;
        atomicAdd(&blockAcc[0], loss_i);
        atomicAdd(&blockAcc[1], (cpa > cnt_) ? 1.0f : 0.0f);
        atomicAdd(&blockAcc[2], (float)cpt);
        atomicAdd(&blockAcc[3], (float)cnt_);
      }
    }
  }
  __syncthreads();
  if (tid < 4) pacc[blockIdx.x * 4 + tid] = blockAcc[tid];
}

// ---- final reduction: 1 block sums 1024 x 4 partials, writes out
__global__ void fin(const float* __restrict__ pacc, float* __restrict__ out) {
  __shared__ float red[256];
  const int tid = threadIdx.x;
  const int c = tid & 3, b0 = tid >> 2;
  float s = 0.0f;
  for (int b = b0; b < MBLK; b += 64) s += pacc[b * 4 + c];
  red[tid] = s;
  __syncthreads();
  if (tid < 4) {
    float t = 0.0f;
    for (int i = tid; i < 256; i += 4) t += red[i];
    out[tid] = t * (1.0f / (float)NPTS);
  }
}

extern "C" void kernel_launch(void* const* d_in, const int* in_sizes, int n_in,
                              void* d_out, int out_size, void* d_ws, size_t ws_size,
                              hipStream_t stream) {
  const float* X = (const float*)d_in[0];
  const long long* targets = (const long long*)d_in[1];
  float* out = (float*)d_out;

  char* ws = (char*)d_ws;
  unsigned short* Xb = (unsigned short*)ws;                        // 2 MiB
  float* sqv    = (float*)   (ws + (2u << 20));                    // 32 KiB
  int*   tgt    = (int*)     (ws + (2u << 20) + (32u << 10));      // 32 KiB
  int*   ccount = (int*)     (ws + (2u << 20) + (64u << 10));      // 512 B
  int*   j0a    = (int*)     (ws + (2u << 20) + (65u << 10));      // 512 B
  int*   j1a    = (int*)     (ws + (2u << 20) + (66u << 10));      // 512 B
  float* pacc   = (float*)   (ws + (2u << 20) + (68u << 10));      // 16 KiB (1024 x 4)
  float* scr = (float*)(ws + (2u << 20) + (128u << 10));           // 8192*8*SEG*4 = 8 MiB
  int* cscr  = (int*)  (ws + (2u << 20) + (128u << 10) +
                        (size_t)NPTS * NSEG * SEG * 4);            // 256 KiB

  prep<<<2049, 256, 0, stream>>>(X, targets, Xb, sqv, tgt, ccount, j0a, j1a);
  knn_main<<<1024, 256, 0, stream>>>(Xb, sqv, tgt, scr, cscr);
  knn_merge<<<MBLK, 256, 0, stream>>>(scr, cscr, sqv, tgt, ccount, j0a, j1a, X, pacc);
  fin<<<1, 256, 0, stream>>>(pacc, out);
}